// Round 1
// baseline (542.493 us; speedup 1.0000x reference)
//
#include <hip/hip_runtime.h>
#include <stdint.h>

typedef unsigned short ushort_t;
typedef __attribute__((ext_vector_type(8))) short short8;
typedef __attribute__((ext_vector_type(4))) float f32x4;

#define BATCH 4
#define SEQ 2048
#define DMODEL 768
#define NH 12
#define HD 64
#define QKV3 2304

__device__ __forceinline__ ushort_t f2bf(float f) {
    union { float f; uint32_t u; } v; v.f = f;
    uint32_t u = v.u;
    u += 0x7FFF + ((u >> 16) & 1);   // round-to-nearest-even
    return (ushort_t)(u >> 16);
}

// ---------------------------------------------------------------------------
// GEMM1: qkv[8192,2304] = x[8192,768] @ w_qkv[768,2304], fp32 in, bf16 out
// scattered into [3][B][H][N][D] layout; Q pre-scaled by 1/8.
// ---------------------------------------------------------------------------
__global__ __launch_bounds__(256, 2) void gemm_qkv(
    const float* __restrict__ x, const float* __restrict__ w,
    ushort_t* __restrict__ qkv) {
    __shared__ ushort_t As[128][40];   // [m][k], pad 40 for banks, 16B-aligned rows
    __shared__ ushort_t Bs[128][40];   // [n][k] transposed

    const int tid = threadIdx.x;
    const int m0 = blockIdx.y * 128;
    const int n0 = blockIdx.x * 128;
    const int lane = tid & 63, wid = tid >> 6;
    const int wm = wid >> 1, wn = wid & 1;
    const int l16 = lane & 15, quad = lane >> 4;

    f32x4 acc[4][4];
#pragma unroll
    for (int i = 0; i < 4; i++)
#pragma unroll
        for (int j = 0; j < 4; j++) acc[i][j] = (f32x4){0.f, 0.f, 0.f, 0.f};

    for (int kt = 0; kt < DMODEL; kt += 32) {
        // stage A: 128x32, float4 loads, bf16 convert, ushort4 LDS writes
#pragma unroll
        for (int j = 0; j < 4; j++) {
            int f = tid + j * 256;            // 1024 float4 groups
            int row = f >> 3, c4 = (f & 7) * 4;
            float4 v = *(const float4*)(x + (size_t)(m0 + row) * DMODEL + kt + c4);
            ushort4 o;
            o.x = f2bf(v.x); o.y = f2bf(v.y); o.z = f2bf(v.z); o.w = f2bf(v.w);
            *(ushort4*)&As[row][c4] = o;
        }
        // stage B transposed: 32(k) x 128(n)
#pragma unroll
        for (int j = 0; j < 4; j++) {
            int f = tid + j * 256;
            int k = f >> 5, n4 = (f & 31) * 4;
            float4 v = *(const float4*)(w + (size_t)(kt + k) * QKV3 + n0 + n4);
            Bs[n4 + 0][k] = f2bf(v.x);
            Bs[n4 + 1][k] = f2bf(v.y);
            Bs[n4 + 2][k] = f2bf(v.z);
            Bs[n4 + 3][k] = f2bf(v.w);
        }
        __syncthreads();

        short8 a[4], b[4];
#pragma unroll
        for (int mi = 0; mi < 4; mi++)
            a[mi] = *(const short8*)&As[wm * 64 + mi * 16 + l16][quad * 8];
#pragma unroll
        for (int ni = 0; ni < 4; ni++)
            b[ni] = *(const short8*)&Bs[wn * 64 + ni * 16 + l16][quad * 8];
#pragma unroll
        for (int mi = 0; mi < 4; mi++)
#pragma unroll
            for (int ni = 0; ni < 4; ni++)
                acc[mi][ni] = __builtin_amdgcn_mfma_f32_16x16x32_bf16(
                    a[mi], b[ni], acc[mi][ni], 0, 0, 0);
        __syncthreads();
    }

    // epilogue: scatter to [which][b][h][n][d], scale q by 0.125
#pragma unroll
    for (int ni = 0; ni < 4; ni++) {
        int nbase = n0 + wn * 64 + ni * 16;
        int which = nbase / DMODEL;
        int rem = nbase - which * DMODEL;
        int h = rem >> 6;
        int d = (rem & 63) + l16;
        float scale = (which == 0) ? 0.125f : 1.0f;
#pragma unroll
        for (int mi = 0; mi < 4; mi++) {
#pragma unroll
            for (int r = 0; r < 4; r++) {
                int mg = m0 + wm * 64 + mi * 16 + quad * 4 + r;
                int b_ = mg >> 11, ns = mg & 2047;
                size_t dst = (((size_t)(which * BATCH + b_) * NH + h) * SEQ + ns) * HD + d;
                qkv[dst] = f2bf(acc[mi][ni][r] * scale);
            }
        }
    }
}

// ---------------------------------------------------------------------------
// Flash attention: one block = one (b,h) head x 128-row Q tile.
// 4 waves, each owns 32 Q rows. 64-key tiles, online softmax.
// ---------------------------------------------------------------------------
__global__ __launch_bounds__(256, 2) void attn(
    const ushort_t* __restrict__ qkv, ushort_t* __restrict__ attn_out) {
    __shared__ ushort_t Ks[64][72];    // [key][d]
    __shared__ ushort_t Vs[64][72];    // [d][key]  (transposed)
    __shared__ ushort_t Ps[128][72];   // [qrow][key] per-wave 32-row slices

    const int tid = threadIdx.x;
    const int blk = blockIdx.x;
    const int bh = blk >> 4;           // 0..47
    const int qt = blk & 15;           // Q tile
    const int lane = tid & 63, w = tid >> 6;
    const int l16 = lane & 15, quad = lane >> 4;

    const ushort_t* qh = qkv + (size_t)bh * SEQ * HD;
    const ushort_t* kh = qkv + (size_t)(48 + bh) * SEQ * HD;
    const ushort_t* vh = qkv + (size_t)(96 + bh) * SEQ * HD;

    // Q fragments in registers for entire kernel (A-layout: row=l16, k=quad*8+j)
    short8 aq[2][2];
#pragma unroll
    for (int mi = 0; mi < 2; mi++)
#pragma unroll
        for (int kk = 0; kk < 2; kk++) {
            int row = qt * 128 + w * 32 + mi * 16 + l16;
            aq[mi][kk] = *(const short8*)(qh + (size_t)row * HD + kk * 32 + quad * 8);
        }

    float m_i[2][4], l_i[2][4];
    f32x4 O[2][4];
#pragma unroll
    for (int mi = 0; mi < 2; mi++)
#pragma unroll
        for (int r = 0; r < 4; r++) { m_i[mi][r] = -1e30f; l_i[mi][r] = 0.f; }
#pragma unroll
    for (int mi = 0; mi < 2; mi++)
#pragma unroll
        for (int nd = 0; nd < 4; nd++) O[mi][nd] = (f32x4){0.f, 0.f, 0.f, 0.f};

    for (int j0 = 0; j0 < SEQ; j0 += 64) {
        // stage K (natural) and V (transposed)
#pragma unroll
        for (int i = 0; i < 2; i++) {
            int g = tid + i * 256;         // 512 groups of 8 elems
            int row = g >> 3, d8 = (g & 7) * 8;
            *(short8*)&Ks[row][d8] = *(const short8*)(kh + (size_t)(j0 + row) * HD + d8);
        }
#pragma unroll
        for (int i = 0; i < 2; i++) {
            int g = tid + i * 256;
            int row = g >> 3, d8 = (g & 7) * 8;
            short8 vv = *(const short8*)(vh + (size_t)(j0 + row) * HD + d8);
#pragma unroll
            for (int e = 0; e < 8; e++) Vs[d8 + e][row] = (ushort_t)vv[e];
        }
        __syncthreads();

        // S = Q K^T  (Q pre-scaled)
        f32x4 S[2][4];
#pragma unroll
        for (int mi = 0; mi < 2; mi++)
#pragma unroll
            for (int ni = 0; ni < 4; ni++) S[mi][ni] = (f32x4){0.f, 0.f, 0.f, 0.f};
#pragma unroll
        for (int kk = 0; kk < 2; kk++)
#pragma unroll
            for (int ni = 0; ni < 4; ni++) {
                short8 bk = *(const short8*)&Ks[ni * 16 + l16][kk * 32 + quad * 8];
#pragma unroll
                for (int mi = 0; mi < 2; mi++)
                    S[mi][ni] = __builtin_amdgcn_mfma_f32_16x16x32_bf16(
                        aq[mi][kk], bk, S[mi][ni], 0, 0, 0);
            }

        // online softmax per row; write P (bf16) to LDS
#pragma unroll
        for (int mi = 0; mi < 2; mi++) {
#pragma unroll
            for (int r = 0; r < 4; r++) {
                float rmax = S[mi][0][r];
#pragma unroll
                for (int ni = 1; ni < 4; ni++) rmax = fmaxf(rmax, S[mi][ni][r]);
#pragma unroll
                for (int xm = 1; xm < 16; xm <<= 1)
                    rmax = fmaxf(rmax, __shfl_xor(rmax, xm, 64));
                float mnew = fmaxf(m_i[mi][r], rmax);
                float alpha = __expf(m_i[mi][r] - mnew);
                m_i[mi][r] = mnew;
                float rsum = 0.f;
#pragma unroll
                for (int ni = 0; ni < 4; ni++) {
                    float p = __expf(S[mi][ni][r] - mnew);
                    S[mi][ni][r] = p;
                    rsum += p;
                }
#pragma unroll
                for (int xm = 1; xm < 16; xm <<= 1)
                    rsum += __shfl_xor(rsum, xm, 64);
                l_i[mi][r] = l_i[mi][r] * alpha + rsum;
#pragma unroll
                for (int nd = 0; nd < 4; nd++) O[mi][nd][r] *= alpha;
#pragma unroll
                for (int ni = 0; ni < 4; ni++)
                    Ps[w * 32 + mi * 16 + quad * 4 + r][ni * 16 + l16] =
                        f2bf(S[mi][ni][r]);
            }
        }

        // O += P V   (A-frags from Ps, B-frags from Vs)
#pragma unroll
        for (int kk = 0; kk < 2; kk++) {
            short8 ap[2];
#pragma unroll
            for (int mi = 0; mi < 2; mi++)
                ap[mi] = *(const short8*)&Ps[w * 32 + mi * 16 + l16][kk * 32 + quad * 8];
#pragma unroll
            for (int nd = 0; nd < 4; nd++) {
                short8 bv = *(const short8*)&Vs[nd * 16 + l16][kk * 32 + quad * 8];
#pragma unroll
                for (int mi = 0; mi < 2; mi++)
                    O[mi][nd] = __builtin_amdgcn_mfma_f32_16x16x32_bf16(
                        ap[mi], bv, O[mi][nd], 0, 0, 0);
            }
        }
        __syncthreads();
    }

    // epilogue: normalize and write attn_out[b][n][h*64+d] bf16
    const int b_ = bh / NH, h = bh % NH;
#pragma unroll
    for (int mi = 0; mi < 2; mi++)
#pragma unroll
        for (int r = 0; r < 4; r++) {
            int nrow = qt * 128 + w * 32 + mi * 16 + quad * 4 + r;
            float inv = 1.0f / l_i[mi][r];
#pragma unroll
            for (int nd = 0; nd < 4; nd++) {
                int col = h * HD + nd * 16 + l16;
                attn_out[((size_t)(b_ * SEQ + nrow)) * DMODEL + col] =
                    f2bf(O[mi][nd][r] * inv);
            }
        }
}

// ---------------------------------------------------------------------------
// GEMM2: out[8192,768] = attn_out_bf16 @ w_out[768,768] + b_out, fp32 out
// ---------------------------------------------------------------------------
__global__ __launch_bounds__(256, 2) void gemm_out(
    const ushort_t* __restrict__ a_in, const float* __restrict__ w,
    const float* __restrict__ bias, float* __restrict__ out) {
    __shared__ ushort_t As[128][40];
    __shared__ ushort_t Bs[128][40];

    const int tid = threadIdx.x;
    const int m0 = blockIdx.y * 128;
    const int n0 = blockIdx.x * 128;
    const int lane = tid & 63, wid = tid >> 6;
    const int wm = wid >> 1, wn = wid & 1;
    const int l16 = lane & 15, quad = lane >> 4;

    f32x4 acc[4][4];
#pragma unroll
    for (int i = 0; i < 4; i++)
#pragma unroll
        for (int j = 0; j < 4; j++) acc[i][j] = (f32x4){0.f, 0.f, 0.f, 0.f};

    for (int kt = 0; kt < DMODEL; kt += 32) {
        // stage A (already bf16): direct 16B copies
#pragma unroll
        for (int jj = 0; jj < 2; jj++) {
            int g = tid + jj * 256;        // 512 groups of 8
            int row = g >> 2, c8 = (g & 3) * 8;
            *(short8*)&As[row][c8] =
                *(const short8*)(a_in + (size_t)(m0 + row) * DMODEL + kt + c8);
        }
        // stage B transposed + convert
#pragma unroll
        for (int j = 0; j < 4; j++) {
            int f = tid + j * 256;
            int k = f >> 5, n4 = (f & 31) * 4;
            float4 v = *(const float4*)(w + (size_t)(kt + k) * DMODEL + n0 + n4);
            Bs[n4 + 0][k] = f2bf(v.x);
            Bs[n4 + 1][k] = f2bf(v.y);
            Bs[n4 + 2][k] = f2bf(v.z);
            Bs[n4 + 3][k] = f2bf(v.w);
        }
        __syncthreads();

        short8 a[4], b[4];
#pragma unroll
        for (int mi = 0; mi < 4; mi++)
            a[mi] = *(const short8*)&As[wm * 64 + mi * 16 + l16][quad * 8];
#pragma unroll
        for (int ni = 0; ni < 4; ni++)
            b[ni] = *(const short8*)&Bs[wn * 64 + ni * 16 + l16][quad * 8];
#pragma unroll
        for (int mi = 0; mi < 4; mi++)
#pragma unroll
            for (int ni = 0; ni < 4; ni++)
                acc[mi][ni] = __builtin_amdgcn_mfma_f32_16x16x32_bf16(
                    a[mi], b[ni], acc[mi][ni], 0, 0, 0);
        __syncthreads();
    }

#pragma unroll
    for (int ni = 0; ni < 4; ni++) {
        int ng = n0 + wn * 64 + ni * 16 + l16;
        float bv = bias[ng];
#pragma unroll
        for (int mi = 0; mi < 4; mi++) {
#pragma unroll
            for (int r = 0; r < 4; r++) {
                int mg = m0 + wm * 64 + mi * 16 + quad * 4 + r;
                out[(size_t)mg * DMODEL + ng] = acc[mi][ni][r] + bv;
            }
        }
    }
}

extern "C" void kernel_launch(void* const* d_in, const int* in_sizes, int n_in,
                              void* d_out, int out_size, void* d_ws, size_t ws_size,
                              hipStream_t stream) {
    const float* x     = (const float*)d_in[0];
    const float* w_qkv = (const float*)d_in[1];
    const float* w_out = (const float*)d_in[2];
    const float* b_out = (const float*)d_in[3];
    float* out = (float*)d_out;

    ushort_t* qkv = (ushort_t*)d_ws;                          // [3][4][12][2048][64] bf16
    ushort_t* attn_o = qkv + (size_t)3 * BATCH * NH * SEQ * HD;  // [8192][768] bf16

    dim3 g1(QKV3 / 128, (BATCH * SEQ) / 128);   // 18 x 64
    gemm_qkv<<<g1, 256, 0, stream>>>(x, w_qkv, qkv);

    attn<<<dim3(BATCH * NH * (SEQ / 128)), 256, 0, stream>>>(qkv, attn_o);

    dim3 g2(DMODEL / 128, (BATCH * SEQ) / 128); // 6 x 64
    gemm_out<<<g2, 256, 0, stream>>>(attn_o, w_out, b_out, out);
}

// Round 2
// 302.377 us; speedup vs baseline: 1.7941x; 1.7941x over previous
//
#include <hip/hip_runtime.h>
#include <stdint.h>

typedef unsigned short ushort_t;
typedef __attribute__((ext_vector_type(8))) short short8;
typedef __attribute__((ext_vector_type(4))) float f32x4;

#define BATCH 4
#define SEQ 2048
#define DMODEL 768
#define NH 12
#define HD 64
#define QKV3 2304
#define NHEADS 48
// 0.125 (1/sqrt(64)) * log2(e): Q pre-scaled so softmax uses exp2
#define SCALE_Q 0.18033688011112042f

__device__ __forceinline__ ushort_t f2bf(float f) {
    union { float f; uint32_t u; } v; v.f = f;
    uint32_t u = v.u;
    u += 0x7FFF + ((u >> 16) & 1);   // RNE
    return (ushort_t)(u >> 16);
}
__device__ __forceinline__ ushort_t f2bf_trunc(float f) {
    union { float f; uint32_t u; } v; v.f = f;
    return (ushort_t)(v.u >> 16);
}

// async global->LDS, 16B per lane; LDS dst = wave-uniform base + lane*16
typedef __attribute__((address_space(1))) uint32_t as1_u32;
typedef __attribute__((address_space(3))) uint32_t as3_u32;
__device__ __forceinline__ void async16(void* lds, const void* gsrc) {
    __builtin_amdgcn_global_load_lds((as1_u32*)gsrc, (as3_u32*)lds, 16, 0, 0);
}

// 16-lane cross-lane reductions on the VALU pipe (DPP row_ror), not LDS
template <int CTRL>
__device__ __forceinline__ float dpp_mov_f(float x) {
    return __builtin_bit_cast(float,
        __builtin_amdgcn_update_dpp(0, __builtin_bit_cast(int, x), CTRL, 0xF, 0xF, true));
}
__device__ __forceinline__ float red16_max(float x) {
    x = fmaxf(x, dpp_mov_f<0x121>(x));
    x = fmaxf(x, dpp_mov_f<0x122>(x));
    x = fmaxf(x, dpp_mov_f<0x124>(x));
    x = fmaxf(x, dpp_mov_f<0x128>(x));
    return x;
}
__device__ __forceinline__ float red16_sum(float x) {
    x += dpp_mov_f<0x121>(x);
    x += dpp_mov_f<0x122>(x);
    x += dpp_mov_f<0x124>(x);
    x += dpp_mov_f<0x128>(x);
    return x;
}

// ---------------------------------------------------------------------------
// prep: fp32 -> bf16 copy
// ---------------------------------------------------------------------------
__global__ __launch_bounds__(256) void cvt_bf16(
    const float* __restrict__ in, ushort_t* __restrict__ out) {
    int i = blockIdx.x * 256 + threadIdx.x;
    float4 v = *(const float4*)(in + (size_t)i * 4);
    ushort4 o; o.x = f2bf(v.x); o.y = f2bf(v.y); o.z = f2bf(v.z); o.w = f2bf(v.w);
    *(ushort4*)(out + (size_t)i * 4) = o;
}

// prep: fp32 [R][C] -> bf16 [C][R] (64x64 tiles)
__global__ __launch_bounds__(256) void transpose_f32_bf16(
    const float* __restrict__ in, ushort_t* __restrict__ out, int R, int C) {
    __shared__ ushort_t t[64][72];
    const int tid = threadIdx.x;
    const int r0 = blockIdx.y * 64, c0 = blockIdx.x * 64;
#pragma unroll
    for (int i = 0; i < 4; i++) {
        int idx = tid + i * 256;
        int row = idx >> 4, c4 = (idx & 15) * 4;
        float4 v = *(const float4*)(in + (size_t)(r0 + row) * C + c0 + c4);
        ushort4 o; o.x = f2bf(v.x); o.y = f2bf(v.y); o.z = f2bf(v.z); o.w = f2bf(v.w);
        *(ushort4*)&t[row][c4] = o;
    }
    __syncthreads();
#pragma unroll
    for (int i = 0; i < 2; i++) {
        int idx = tid + i * 256;
        int oc = idx >> 3, g8 = (idx & 7) * 8;
        ushort_t tmp[8];
#pragma unroll
        for (int e = 0; e < 8; e++) tmp[e] = t[g8 + e][oc];
        *(short8*)(out + (size_t)(c0 + oc) * R + r0 + g8) = *(const short8*)tmp;
    }
}

// prep: V [head][2048][64] bf16 -> VT [head][64][2048] bf16
__global__ __launch_bounds__(256) void transpose_v(
    const ushort_t* __restrict__ v, ushort_t* __restrict__ vt) {
    __shared__ ushort_t t[64][72];
    const int tid = threadIdx.x;
    const int head = blockIdx.y, n0 = blockIdx.x * 64;
    const ushort_t* src = v + (size_t)head * SEQ * HD + (size_t)n0 * HD;
#pragma unroll
    for (int i = 0; i < 2; i++) {
        int idx = tid + i * 256;
        int row = idx >> 3, c8 = (idx & 7) * 8;
        *(short8*)&t[row][c8] = *(const short8*)(src + (size_t)row * HD + c8);
    }
    __syncthreads();
    ushort_t* dst = vt + (size_t)head * HD * SEQ + n0;
#pragma unroll
    for (int i = 0; i < 2; i++) {
        int idx = tid + i * 256;
        int d = idx >> 3, g8 = (idx & 7) * 8;
        ushort_t tmp[8];
#pragma unroll
        for (int e = 0; e < 8; e++) tmp[e] = t[g8 + e][d];
        *(short8*)(dst + (size_t)d * SEQ + g8) = *(const short8*)tmp;
    }
}

// ---------------------------------------------------------------------------
// GEMM1: qkv = xb[8192,768] @ wqT[2304,768]^T, bf16 in/out, m97-style staging
// epilogue scatters to [3][B][H][N][D]; Q pre-scaled by SCALE_Q.
// ---------------------------------------------------------------------------
__global__ __launch_bounds__(256, 2) void gemm_qkv(
    const ushort_t* __restrict__ A, const ushort_t* __restrict__ B,
    ushort_t* __restrict__ qkv) {
    __shared__ ushort_t As[128 * 64];   // XOR-swizzled 16B columns, no pad
    __shared__ ushort_t Bs[128 * 64];

    const int tid = threadIdx.x;
    const int m0 = blockIdx.y * 128, n0 = blockIdx.x * 128;
    const int lane = tid & 63, w = tid >> 6;
    const int wm = w >> 1, wn = w & 1;
    const int l16 = lane & 15, quad = lane >> 4;

    f32x4 acc[4][4];
#pragma unroll
    for (int i = 0; i < 4; i++)
#pragma unroll
        for (int j = 0; j < 4; j++) acc[i][j] = (f32x4){0.f, 0.f, 0.f, 0.f};

    int srow[4], scol[4];
#pragma unroll
    for (int j = 0; j < 4; j++) {
        int s = j * 256 + tid;
        srow[j] = s >> 3;
        scol[j] = ((s & 7) ^ (srow[j] & 7)) * 8;
    }
    const int swz0 = (quad ^ (l16 & 7)) * 8;
    const int swz1 = ((4 + quad) ^ (l16 & 7)) * 8;

    for (int kt = 0; kt < DMODEL; kt += 64) {
#pragma unroll
        for (int j = 0; j < 4; j++) {
            async16(&As[(j * 256 + w * 64) * 8],
                    A + (size_t)(m0 + srow[j]) * DMODEL + kt + scol[j]);
            async16(&Bs[(j * 256 + w * 64) * 8],
                    B + (size_t)(n0 + srow[j]) * DMODEL + kt + scol[j]);
        }
        __syncthreads();

        short8 a[4][2], b[4][2];
#pragma unroll
        for (int mi = 0; mi < 4; mi++) {
            int r = (wm * 64 + mi * 16 + l16) * 64;
            a[mi][0] = *(const short8*)&As[r + swz0];
            a[mi][1] = *(const short8*)&As[r + swz1];
        }
#pragma unroll
        for (int ni = 0; ni < 4; ni++) {
            int r = (wn * 64 + ni * 16 + l16) * 64;
            b[ni][0] = *(const short8*)&Bs[r + swz0];
            b[ni][1] = *(const short8*)&Bs[r + swz1];
        }
#pragma unroll
        for (int kk = 0; kk < 2; kk++)
#pragma unroll
            for (int mi = 0; mi < 4; mi++)
#pragma unroll
                for (int ni = 0; ni < 4; ni++)
                    acc[mi][ni] = __builtin_amdgcn_mfma_f32_16x16x32_bf16(
                        a[mi][kk], b[ni][kk], acc[mi][ni], 0, 0, 0);
        __syncthreads();
    }

#pragma unroll
    for (int ni = 0; ni < 4; ni++) {
        int nbase = n0 + wn * 64 + ni * 16;
        int which = nbase / DMODEL;
        int rem = nbase - which * DMODEL;
        int h = rem >> 6;
        int d = (rem & 63) + l16;
        float scale = (which == 0) ? SCALE_Q : 1.0f;
#pragma unroll
        for (int mi = 0; mi < 4; mi++) {
#pragma unroll
            for (int r = 0; r < 4; r++) {
                int mg = m0 + wm * 64 + mi * 16 + quad * 4 + r;
                int b_ = mg >> 11, ns = mg & 2047;
                size_t dst = (((size_t)(which * BATCH + b_) * NH + h) * SEQ + ns) * HD + d;
                qkv[dst] = f2bf(acc[mi][ni][r] * scale);
            }
        }
    }
}

// ---------------------------------------------------------------------------
// Flash attention, V pre-transposed. One block = (b,h) x 128-row Q tile.
// ---------------------------------------------------------------------------
__global__ __launch_bounds__(256, 2) void attn(
    const ushort_t* __restrict__ qkv, const ushort_t* __restrict__ vT,
    ushort_t* __restrict__ ao) {
    __shared__ ushort_t Ks[64 * 64];   // swizzled [key][d]
    __shared__ ushort_t Vs[64 * 64];   // swizzled [d][key]
    __shared__ ushort_t Ps[128][72];   // [qrow][key]

    const int tid = threadIdx.x;
    const int bh = blockIdx.x >> 4, qt = blockIdx.x & 15;
    const int lane = tid & 63, w = tid >> 6;
    const int l16 = lane & 15, quad = lane >> 4;

    const ushort_t* qh = qkv + (size_t)bh * (SEQ * HD);
    const ushort_t* kh = qkv + (size_t)(NHEADS + bh) * (SEQ * HD);
    const ushort_t* vh = vT + (size_t)bh * (HD * SEQ);

    short8 aq[2][2];
#pragma unroll
    for (int mi = 0; mi < 2; mi++)
#pragma unroll
        for (int kk = 0; kk < 2; kk++) {
            int row = qt * 128 + w * 32 + mi * 16 + l16;
            aq[mi][kk] = *(const short8*)(qh + (size_t)row * HD + kk * 32 + quad * 8);
        }

    float m_i[2][4], l_i[2][4];
    f32x4 O[2][4];
#pragma unroll
    for (int mi = 0; mi < 2; mi++)
#pragma unroll
        for (int r = 0; r < 4; r++) { m_i[mi][r] = -1e30f; l_i[mi][r] = 0.f; }
#pragma unroll
    for (int mi = 0; mi < 2; mi++)
#pragma unroll
        for (int nd = 0; nd < 4; nd++) O[mi][nd] = (f32x4){0.f, 0.f, 0.f, 0.f};

    int srow[2], scol[2];
#pragma unroll
    for (int j = 0; j < 2; j++) {
        int s = j * 256 + tid;
        srow[j] = s >> 3;
        scol[j] = ((s & 7) ^ (srow[j] & 7)) * 8;
    }
    const int swz0 = (quad ^ (l16 & 7)) * 8;
    const int swz1 = ((4 + quad) ^ (l16 & 7)) * 8;

    for (int j0 = 0; j0 < SEQ; j0 += 64) {
#pragma unroll
        for (int j = 0; j < 2; j++) {
            async16(&Ks[(j * 256 + w * 64) * 8],
                    kh + (size_t)(j0 + srow[j]) * HD + scol[j]);
            async16(&Vs[(j * 256 + w * 64) * 8],
                    vh + (size_t)srow[j] * SEQ + j0 + scol[j]);
        }
        __syncthreads();

        // S = Q K^T
        f32x4 S[2][4];
#pragma unroll
        for (int mi = 0; mi < 2; mi++)
#pragma unroll
            for (int ni = 0; ni < 4; ni++) S[mi][ni] = (f32x4){0.f, 0.f, 0.f, 0.f};
        short8 bk[4][2];
#pragma unroll
        for (int ni = 0; ni < 4; ni++) {
            int r = (ni * 16 + l16) * 64;
            bk[ni][0] = *(const short8*)&Ks[r + swz0];
            bk[ni][1] = *(const short8*)&Ks[r + swz1];
        }
#pragma unroll
        for (int kk = 0; kk < 2; kk++)
#pragma unroll
            for (int ni = 0; ni < 4; ni++)
#pragma unroll
                for (int mi = 0; mi < 2; mi++)
                    S[mi][ni] = __builtin_amdgcn_mfma_f32_16x16x32_bf16(
                        aq[mi][kk], bk[ni][kk], S[mi][ni], 0, 0, 0);

        // online softmax (exp2 domain); DPP max-reduce; deferred l-sum
#pragma unroll
        for (int mi = 0; mi < 2; mi++) {
#pragma unroll
            for (int r = 0; r < 4; r++) {
                float v0 = fmaxf(fmaxf(S[mi][0][r], S[mi][1][r]),
                                 fmaxf(S[mi][2][r], S[mi][3][r]));
                float rmax = red16_max(v0);
                float mnew = fmaxf(m_i[mi][r], rmax);
                float alpha = exp2f(m_i[mi][r] - mnew);
                m_i[mi][r] = mnew;
                float ps = 0.f;
#pragma unroll
                for (int ni = 0; ni < 4; ni++) {
                    float p = exp2f(S[mi][ni][r] - mnew);
                    ps += p;
                    Ps[w * 32 + mi * 16 + quad * 4 + r][ni * 16 + l16] = f2bf_trunc(p);
                }
                l_i[mi][r] = l_i[mi][r] * alpha + ps;
#pragma unroll
                for (int nd = 0; nd < 4; nd++) O[mi][nd][r] *= alpha;
            }
        }

        // O += P V
        short8 ap[2][2], bv[4][2];
#pragma unroll
        for (int mi = 0; mi < 2; mi++)
#pragma unroll
            for (int kk = 0; kk < 2; kk++)
                ap[mi][kk] = *(const short8*)&Ps[w * 32 + mi * 16 + l16][kk * 32 + quad * 8];
#pragma unroll
        for (int nd = 0; nd < 4; nd++) {
            int r = (nd * 16 + l16) * 64;
            bv[nd][0] = *(const short8*)&Vs[r + swz0];
            bv[nd][1] = *(const short8*)&Vs[r + swz1];
        }
#pragma unroll
        for (int kk = 0; kk < 2; kk++)
#pragma unroll
            for (int nd = 0; nd < 4; nd++)
#pragma unroll
                for (int mi = 0; mi < 2; mi++)
                    O[mi][nd] = __builtin_amdgcn_mfma_f32_16x16x32_bf16(
                        ap[mi][kk], bv[nd][kk], O[mi][nd], 0, 0, 0);
        __syncthreads();
    }

    const int b_ = bh / NH, h = bh % NH;
#pragma unroll
    for (int mi = 0; mi < 2; mi++)
#pragma unroll
        for (int r = 0; r < 4; r++) {
            float lsum = red16_sum(l_i[mi][r]);
            float inv = __builtin_amdgcn_rcpf(lsum);
            int nrow = qt * 128 + w * 32 + mi * 16 + quad * 4 + r;
#pragma unroll
            for (int nd = 0; nd < 4; nd++) {
                int col = h * HD + nd * 16 + l16;
                ao[((size_t)(b_ * SEQ + nrow)) * DMODEL + col] = f2bf(O[mi][nd][r] * inv);
            }
        }
}

// ---------------------------------------------------------------------------
// GEMM2: out[8192,768] = ao_bf16 @ woT[768,768]^T + bias, fp32 out
// ---------------------------------------------------------------------------
__global__ __launch_bounds__(256, 2) void gemm_out(
    const ushort_t* __restrict__ A, const ushort_t* __restrict__ B,
    const float* __restrict__ bias, float* __restrict__ out) {
    __shared__ ushort_t As[128 * 64];
    __shared__ ushort_t Bs[128 * 64];

    const int tid = threadIdx.x;
    const int m0 = blockIdx.y * 128, n0 = blockIdx.x * 128;
    const int lane = tid & 63, w = tid >> 6;
    const int wm = w >> 1, wn = w & 1;
    const int l16 = lane & 15, quad = lane >> 4;

    f32x4 acc[4][4];
#pragma unroll
    for (int i = 0; i < 4; i++)
#pragma unroll
        for (int j = 0; j < 4; j++) acc[i][j] = (f32x4){0.f, 0.f, 0.f, 0.f};

    int srow[4], scol[4];
#pragma unroll
    for (int j = 0; j < 4; j++) {
        int s = j * 256 + tid;
        srow[j] = s >> 3;
        scol[j] = ((s & 7) ^ (srow[j] & 7)) * 8;
    }
    const int swz0 = (quad ^ (l16 & 7)) * 8;
    const int swz1 = ((4 + quad) ^ (l16 & 7)) * 8;

    for (int kt = 0; kt < DMODEL; kt += 64) {
#pragma unroll
        for (int j = 0; j < 4; j++) {
            async16(&As[(j * 256 + w * 64) * 8],
                    A + (size_t)(m0 + srow[j]) * DMODEL + kt + scol[j]);
            async16(&Bs[(j * 256 + w * 64) * 8],
                    B + (size_t)(n0 + srow[j]) * DMODEL + kt + scol[j]);
        }
        __syncthreads();

        short8 a[4][2], b[4][2];
#pragma unroll
        for (int mi = 0; mi < 4; mi++) {
            int r = (wm * 64 + mi * 16 + l16) * 64;
            a[mi][0] = *(const short8*)&As[r + swz0];
            a[mi][1] = *(const short8*)&As[r + swz1];
        }
#pragma unroll
        for (int ni = 0; ni < 4; ni++) {
            int r = (wn * 64 + ni * 16 + l16) * 64;
            b[ni][0] = *(const short8*)&Bs[r + swz0];
            b[ni][1] = *(const short8*)&Bs[r + swz1];
        }
#pragma unroll
        for (int kk = 0; kk < 2; kk++)
#pragma unroll
            for (int mi = 0; mi < 4; mi++)
#pragma unroll
                for (int ni = 0; ni < 4; ni++)
                    acc[mi][ni] = __builtin_amdgcn_mfma_f32_16x16x32_bf16(
                        a[mi][kk], b[ni][kk], acc[mi][ni], 0, 0, 0);
        __syncthreads();
    }

#pragma unroll
    for (int ni = 0; ni < 4; ni++) {
        int ng = n0 + wn * 64 + ni * 16 + l16;
        float bv = bias[ng];
#pragma unroll
        for (int mi = 0; mi < 4; mi++) {
#pragma unroll
            for (int r = 0; r < 4; r++) {
                int mg = m0 + wm * 64 + mi * 16 + quad * 4 + r;
                out[(size_t)mg * DMODEL + ng] = acc[mi][ni][r] + bv;
            }
        }
    }
}

extern "C" void kernel_launch(void* const* d_in, const int* in_sizes, int n_in,
                              void* d_out, int out_size, void* d_ws, size_t ws_size,
                              hipStream_t stream) {
    const float* x     = (const float*)d_in[0];
    const float* w_qkv = (const float*)d_in[1];
    const float* w_out = (const float*)d_in[2];
    const float* b_out = (const float*)d_in[3];
    float* out = (float*)d_out;

    ushort_t* xb  = (ushort_t*)d_ws;                       // 8192*768
    ushort_t* wqT = xb  + (size_t)8192 * 768;              // 2304*768
    ushort_t* woT = wqT + (size_t)QKV3 * 768;              // 768*768
    ushort_t* qkv = woT + (size_t)768 * 768;               // 3*48*2048*64
    ushort_t* vT  = qkv + (size_t)3 * NHEADS * SEQ * HD;   // 48*64*2048
    ushort_t* ao  = vT  + (size_t)NHEADS * HD * SEQ;       // 8192*768

    cvt_bf16<<<dim3((8192 * 768) / 4 / 256), 256, 0, stream>>>(x, xb);
    transpose_f32_bf16<<<dim3(QKV3 / 64, DMODEL / 64), 256, 0, stream>>>(
        w_qkv, wqT, DMODEL, QKV3);
    transpose_f32_bf16<<<dim3(DMODEL / 64, DMODEL / 64), 256, 0, stream>>>(
        w_out, woT, DMODEL, DMODEL);

    gemm_qkv<<<dim3(QKV3 / 128, (BATCH * SEQ) / 128), 256, 0, stream>>>(xb, wqT, qkv);

    transpose_v<<<dim3(SEQ / 64, NHEADS), 256, 0, stream>>>(
        qkv + (size_t)2 * NHEADS * SEQ * HD, vT);

    attn<<<dim3(NHEADS * (SEQ / 128)), 256, 0, stream>>>(qkv, vT, ao);

    gemm_out<<<dim3(DMODEL / 128, (BATCH * SEQ) / 128), 256, 0, stream>>>(
        ao, woT, b_out, out);
}

// Round 3
// 249.869 us; speedup vs baseline: 2.1711x; 1.2101x over previous
//
#include <hip/hip_runtime.h>
#include <stdint.h>

typedef unsigned short ushort_t;
typedef __attribute__((ext_vector_type(8))) short short8;
typedef __attribute__((ext_vector_type(4))) short s16x4;
typedef __attribute__((ext_vector_type(4))) float f32x4;
typedef __attribute__((ext_vector_type(2))) uint32_t u32x2;

#define BATCH 4
#define SEQ 2048
#define DMODEL 768
#define NH 12
#define HD 64
#define QKV3 2304
#define NHEADS 48
// 0.125 (1/sqrt(64)) * log2(e): Q pre-scaled so softmax uses exp2
#define SCALE_Q 0.18033688011112042f

__device__ __forceinline__ ushort_t f2bf(float f) {
    union { float f; uint32_t u; } v; v.f = f;
    uint32_t u = v.u;
    u += 0x7FFF + ((u >> 16) & 1);   // RNE
    return (ushort_t)(u >> 16);
}

// async global->LDS, 16B per lane; LDS dst = wave-uniform base + lane*16
typedef __attribute__((address_space(1))) uint32_t as1_u32;
typedef __attribute__((address_space(3))) uint32_t as3_u32;
__device__ __forceinline__ void async16(void* lds, const void* gsrc) {
    __builtin_amdgcn_global_load_lds((as1_u32*)gsrc, (as3_u32*)lds, 16, 0, 0);
}

// K=16 bf16 MFMA (P^T stays in registers as the B operand)
__device__ __forceinline__ f32x4 mfma16x16x16bf16(s16x4 a, s16x4 b, f32x4 c) {
#if __has_builtin(__builtin_amdgcn_mfma_f32_16x16x16bf16_1k)
    return __builtin_amdgcn_mfma_f32_16x16x16bf16_1k(a, b, c, 0, 0, 0);
#else
    f32x4 d;
    asm volatile("v_mfma_f32_16x16x16_bf16 %0, %1, %2, %3"
                 : "=v"(d) : "v"(a), "v"(b), "0"(c));
    return d;
#endif
}

// pack two fp32 -> bf16x2 dword (truncation) with one v_perm
__device__ __forceinline__ uint32_t pack_bf16_trunc(float lo, float hi) {
    return __builtin_amdgcn_perm(__builtin_bit_cast(uint32_t, hi),
                                 __builtin_bit_cast(uint32_t, lo), 0x07060302u);
}

// ---------------------------------------------------------------------------
// prep kernels
// ---------------------------------------------------------------------------
__global__ __launch_bounds__(256) void cvt_bf16(
    const float* __restrict__ in, ushort_t* __restrict__ out) {
    int i = blockIdx.x * 256 + threadIdx.x;
    float4 v = *(const float4*)(in + (size_t)i * 4);
    ushort4 o; o.x = f2bf(v.x); o.y = f2bf(v.y); o.z = f2bf(v.z); o.w = f2bf(v.w);
    *(ushort4*)(out + (size_t)i * 4) = o;
}

__global__ __launch_bounds__(256) void transpose_f32_bf16(
    const float* __restrict__ in, ushort_t* __restrict__ out, int R, int C) {
    __shared__ ushort_t t[64][72];
    const int tid = threadIdx.x;
    const int r0 = blockIdx.y * 64, c0 = blockIdx.x * 64;
#pragma unroll
    for (int i = 0; i < 4; i++) {
        int idx = tid + i * 256;
        int row = idx >> 4, c4 = (idx & 15) * 4;
        float4 v = *(const float4*)(in + (size_t)(r0 + row) * C + c0 + c4);
        ushort4 o; o.x = f2bf(v.x); o.y = f2bf(v.y); o.z = f2bf(v.z); o.w = f2bf(v.w);
        *(ushort4*)&t[row][c4] = o;
    }
    __syncthreads();
#pragma unroll
    for (int i = 0; i < 2; i++) {
        int idx = tid + i * 256;
        int oc = idx >> 3, g8 = (idx & 7) * 8;
        ushort_t tmp[8];
#pragma unroll
        for (int e = 0; e < 8; e++) tmp[e] = t[g8 + e][oc];
        *(short8*)(out + (size_t)(c0 + oc) * R + r0 + g8) = *(const short8*)tmp;
    }
}

__global__ __launch_bounds__(256) void transpose_v(
    const ushort_t* __restrict__ v, ushort_t* __restrict__ vt) {
    __shared__ ushort_t t[64][72];
    const int tid = threadIdx.x;
    const int head = blockIdx.y, n0 = blockIdx.x * 64;
    const ushort_t* src = v + (size_t)head * SEQ * HD + (size_t)n0 * HD;
#pragma unroll
    for (int i = 0; i < 2; i++) {
        int idx = tid + i * 256;
        int row = idx >> 3, c8 = (idx & 7) * 8;
        *(short8*)&t[row][c8] = *(const short8*)(src + (size_t)row * HD + c8);
    }
    __syncthreads();
    ushort_t* dst = vt + (size_t)head * HD * SEQ + n0;
#pragma unroll
    for (int i = 0; i < 2; i++) {
        int idx = tid + i * 256;
        int d = idx >> 3, g8 = (idx & 7) * 8;
        ushort_t tmp[8];
#pragma unroll
        for (int e = 0; e < 8; e++) tmp[e] = t[g8 + e][d];
        *(short8*)(dst + (size_t)d * SEQ + g8) = *(const short8*)tmp;
    }
}

// ---------------------------------------------------------------------------
// GEMM1 (unchanged from R2)
// ---------------------------------------------------------------------------
__global__ __launch_bounds__(256, 2) void gemm_qkv(
    const ushort_t* __restrict__ A, const ushort_t* __restrict__ B,
    ushort_t* __restrict__ qkv) {
    __shared__ ushort_t As[128 * 64];
    __shared__ ushort_t Bs[128 * 64];

    const int tid = threadIdx.x;
    const int m0 = blockIdx.y * 128, n0 = blockIdx.x * 128;
    const int lane = tid & 63, w = tid >> 6;
    const int wm = w >> 1, wn = w & 1;
    const int l16 = lane & 15, quad = lane >> 4;

    f32x4 acc[4][4];
#pragma unroll
    for (int i = 0; i < 4; i++)
#pragma unroll
        for (int j = 0; j < 4; j++) acc[i][j] = (f32x4){0.f, 0.f, 0.f, 0.f};

    int srow[4], scol[4];
#pragma unroll
    for (int j = 0; j < 4; j++) {
        int s = j * 256 + tid;
        srow[j] = s >> 3;
        scol[j] = ((s & 7) ^ (srow[j] & 7)) * 8;
    }
    const int swz0 = (quad ^ (l16 & 7)) * 8;
    const int swz1 = ((4 + quad) ^ (l16 & 7)) * 8;

    for (int kt = 0; kt < DMODEL; kt += 64) {
#pragma unroll
        for (int j = 0; j < 4; j++) {
            async16(&As[(j * 256 + w * 64) * 8],
                    A + (size_t)(m0 + srow[j]) * DMODEL + kt + scol[j]);
            async16(&Bs[(j * 256 + w * 64) * 8],
                    B + (size_t)(n0 + srow[j]) * DMODEL + kt + scol[j]);
        }
        __syncthreads();

        short8 a[4][2], b[4][2];
#pragma unroll
        for (int mi = 0; mi < 4; mi++) {
            int r = (wm * 64 + mi * 16 + l16) * 64;
            a[mi][0] = *(const short8*)&As[r + swz0];
            a[mi][1] = *(const short8*)&As[r + swz1];
        }
#pragma unroll
        for (int ni = 0; ni < 4; ni++) {
            int r = (wn * 64 + ni * 16 + l16) * 64;
            b[ni][0] = *(const short8*)&Bs[r + swz0];
            b[ni][1] = *(const short8*)&Bs[r + swz1];
        }
#pragma unroll
        for (int kk = 0; kk < 2; kk++)
#pragma unroll
            for (int mi = 0; mi < 4; mi++)
#pragma unroll
                for (int ni = 0; ni < 4; ni++)
                    acc[mi][ni] = __builtin_amdgcn_mfma_f32_16x16x32_bf16(
                        a[mi][kk], b[ni][kk], acc[mi][ni], 0, 0, 0);
        __syncthreads();
    }

#pragma unroll
    for (int ni = 0; ni < 4; ni++) {
        int nbase = n0 + wn * 64 + ni * 16;
        int which = nbase / DMODEL;
        int rem = nbase - which * DMODEL;
        int h = rem >> 6;
        int d = (rem & 63) + l16;
        float scale = (which == 0) ? SCALE_Q : 1.0f;
#pragma unroll
        for (int mi = 0; mi < 4; mi++) {
#pragma unroll
            for (int r = 0; r < 4; r++) {
                int mg = m0 + wm * 64 + mi * 16 + quad * 4 + r;
                int b_ = mg >> 11, ns = mg & 2047;
                size_t dst = (((size_t)(which * BATCH + b_) * NH + h) * SEQ + ns) * HD + d;
                qkv[dst] = f2bf(acc[mi][ni][r] * scale);
            }
        }
    }
}

// ---------------------------------------------------------------------------
// Flash attention, S^T formulation, P in registers, 1 barrier/tile dbuf.
// Block = (b,h) x 128 queries; wave owns 32 queries (2x16 tiles as MFMA N).
// ---------------------------------------------------------------------------
__global__ __launch_bounds__(256, 3) void attn(
    const ushort_t* __restrict__ qkv, const ushort_t* __restrict__ vT,
    ushort_t* __restrict__ ao) {
    // dbuf: buffer b at smem + b*8192: [Ks 64x64 | Vs 64x64]; epilogue reuses.
    __shared__ ushort_t smem[16384];

    const int tid = threadIdx.x;
    const int bh = blockIdx.x >> 4, qt = blockIdx.x & 15;
    const int lane = tid & 63, w = tid >> 6;
    const int l16 = lane & 15, quad = lane >> 4;
    const int qh7 = l16 & 7, qhi = quad >> 1, qlo4 = (quad & 1) * 4;

    const ushort_t* qh = qkv + (size_t)bh * (SEQ * HD);
    const ushort_t* kh = qkv + (size_t)(NHEADS + bh) * (SEQ * HD);
    const ushort_t* vh = vT + (size_t)bh * (HD * SEQ);

    // Q fragments: identical data serves as MFMA B-operand (col=query=l16)
    short8 aq[2][2];
#pragma unroll
    for (int mi = 0; mi < 2; mi++)
#pragma unroll
        for (int kk = 0; kk < 2; kk++) {
            int row = qt * 128 + w * 32 + mi * 16 + l16;
            aq[mi][kk] = *(const short8*)(qh + (size_t)row * HD + kk * 32 + quad * 8);
        }

    float m_i[2], l_i[2];
    f32x4 O[4][2];   // O^T: [nd (d-rows)][mi (query cols)]
#pragma unroll
    for (int mi = 0; mi < 2; mi++) { m_i[mi] = -3.0e38f; l_i[mi] = 0.f; }
#pragma unroll
    for (int nd = 0; nd < 4; nd++)
#pragma unroll
        for (int mi = 0; mi < 2; mi++) O[nd][mi] = (f32x4){0.f, 0.f, 0.f, 0.f};

    int srow[2], scol[2];
#pragma unroll
    for (int j = 0; j < 2; j++) {
        int s = j * 256 + tid;
        srow[j] = s >> 3;
        scol[j] = ((s & 7) ^ (srow[j] & 7)) * 8;
    }
    const int swz0 = (quad ^ qh7) * 8;
    const int swz1 = ((4 + quad) ^ qh7) * 8;

    // prologue: stage tile 0 into buffer 0
#pragma unroll
    for (int j = 0; j < 2; j++) {
        async16(&smem[(j * 256 + w * 64) * 8],
                kh + (size_t)srow[j] * HD + scol[j]);
        async16(&smem[4096 + (j * 256 + w * 64) * 8],
                vh + (size_t)srow[j] * SEQ + scol[j]);
    }

    const int NT = SEQ / 64;
    for (int t = 0; t < NT; t++) {
        __syncthreads();   // drains vmcnt: tile t ready; prev compute done
        if (t + 1 < NT) {
            int nb = ((t + 1) & 1) * 8192, j1 = (t + 1) * 64;
#pragma unroll
            for (int j = 0; j < 2; j++) {
                async16(&smem[nb + (j * 256 + w * 64) * 8],
                        kh + (size_t)(j1 + srow[j]) * HD + scol[j]);
                async16(&smem[nb + 4096 + (j * 256 + w * 64) * 8],
                        vh + (size_t)srow[j] * SEQ + j1 + scol[j]);
            }
        }
        const ushort_t* Ks = smem + (t & 1) * 8192;
        const ushort_t* Vs = Ks + 4096;

        // S^T[ni=key tile][mi=query tile] = mfma(A=K, B=Q)
        f32x4 S[4][2];
#pragma unroll
        for (int ni = 0; ni < 4; ni++)
#pragma unroll
            for (int mi = 0; mi < 2; mi++) S[ni][mi] = (f32x4){0.f, 0.f, 0.f, 0.f};
        short8 ak[4][2];
#pragma unroll
        for (int ni = 0; ni < 4; ni++) {
            int r = (ni * 16 + l16) * 64;
            ak[ni][0] = *(const short8*)&Ks[r + swz0];
            ak[ni][1] = *(const short8*)&Ks[r + swz1];
        }
#pragma unroll
        for (int kk = 0; kk < 2; kk++)
#pragma unroll
            for (int ni = 0; ni < 4; ni++)
#pragma unroll
                for (int mi = 0; mi < 2; mi++)
                    S[ni][mi] = __builtin_amdgcn_mfma_f32_16x16x32_bf16(
                        ak[ni][kk], aq[mi][kk], S[ni][mi], 0, 0, 0);

        // online softmax: per lane = one query per mi; 16 keys local + 2 shfl
#pragma unroll
        for (int mi = 0; mi < 2; mi++) {
            float mx = S[0][mi][0];
#pragma unroll
            for (int ni = 0; ni < 4; ni++)
#pragma unroll
                for (int r = 0; r < 4; r++) mx = fmaxf(mx, S[ni][mi][r]);
            mx = fmaxf(mx, __shfl_xor(mx, 16, 64));
            mx = fmaxf(mx, __shfl_xor(mx, 32, 64));
            float mnew = fmaxf(m_i[mi], mx);
            float alpha = exp2f(m_i[mi] - mnew);
            m_i[mi] = mnew;
            float ps = 0.f;
#pragma unroll
            for (int ni = 0; ni < 4; ni++)
#pragma unroll
                for (int r = 0; r < 4; r++) {
                    float p = exp2f(S[ni][mi][r] - mnew);
                    S[ni][mi][r] = p;
                    ps += p;
                }
            l_i[mi] = l_i[mi] * alpha + ps;
#pragma unroll
            for (int nd = 0; nd < 4; nd++)
#pragma unroll
                for (int r = 0; r < 4; r++) O[nd][mi][r] *= alpha;
        }

        // O^T += mfma(A=V^T from LDS, B=P^T packed from S regs), K=16
#pragma unroll
        for (int kb = 0; kb < 4; kb++) {
            s16x4 bp[2];
#pragma unroll
            for (int mi = 0; mi < 2; mi++) {
                uint32_t lo = pack_bf16_trunc(S[kb][mi][0], S[kb][mi][1]);
                uint32_t hi = pack_bf16_trunc(S[kb][mi][2], S[kb][mi][3]);
                bp[mi] = __builtin_bit_cast(s16x4, (u32x2){lo, hi});
            }
#pragma unroll
            for (int nd = 0; nd < 4; nd++) {
                int vrow = nd * 16 + l16;
                s16x4 av = *(const s16x4*)&Vs[vrow * 64 +
                                              (((kb * 2 + qhi) ^ qh7) * 8) + qlo4];
#pragma unroll
                for (int mi = 0; mi < 2; mi++)
                    O[nd][mi] = mfma16x16x16bf16(av, bp[mi], O[nd][mi]);
            }
        }
    }

    // epilogue: l-reduce across quads, transpose O^T via LDS, coalesced store
    float inv[2];
#pragma unroll
    for (int mi = 0; mi < 2; mi++) {
        float l = l_i[mi];
        l += __shfl_xor(l, 16, 64);
        l += __shfl_xor(l, 32, 64);
        inv[mi] = __builtin_amdgcn_rcpf(l);
    }
    __syncthreads();
    ushort_t* Lt = smem;   // [128][72]
#pragma unroll
    for (int mi = 0; mi < 2; mi++)
#pragma unroll
        for (int nd = 0; nd < 4; nd++) {
            int row = w * 32 + mi * 16 + l16;
            int col = nd * 16 + quad * 4;
            uint32_t d0 = (uint32_t)f2bf(O[nd][mi][0] * inv[mi]) |
                          ((uint32_t)f2bf(O[nd][mi][1] * inv[mi]) << 16);
            uint32_t d1 = (uint32_t)f2bf(O[nd][mi][2] * inv[mi]) |
                          ((uint32_t)f2bf(O[nd][mi][3] * inv[mi]) << 16);
            *(u32x2*)&Lt[row * 72 + col] = (u32x2){d0, d1};
        }
    __syncthreads();

    const int b_ = bh / NH, h = bh % NH;
#pragma unroll
    for (int i = 0; i < 4; i++) {
        int idx = tid + i * 256;
        int row = idx >> 3, c8 = (idx & 7) * 8;
        short8 vv = *(const short8*)&Lt[row * 72 + c8];
        *(short8*)(ao + ((size_t)(b_ * SEQ + qt * 128 + row)) * DMODEL +
                   h * HD + c8) = vv;
    }
}

// ---------------------------------------------------------------------------
// GEMM2 (unchanged from R2)
// ---------------------------------------------------------------------------
__global__ __launch_bounds__(256, 2) void gemm_out(
    const ushort_t* __restrict__ A, const ushort_t* __restrict__ B,
    const float* __restrict__ bias, float* __restrict__ out) {
    __shared__ ushort_t As[128 * 64];
    __shared__ ushort_t Bs[128 * 64];

    const int tid = threadIdx.x;
    const int m0 = blockIdx.y * 128, n0 = blockIdx.x * 128;
    const int lane = tid & 63, w = tid >> 6;
    const int wm = w >> 1, wn = w & 1;
    const int l16 = lane & 15, quad = lane >> 4;

    f32x4 acc[4][4];
#pragma unroll
    for (int i = 0; i < 4; i++)
#pragma unroll
        for (int j = 0; j < 4; j++) acc[i][j] = (f32x4){0.f, 0.f, 0.f, 0.f};

    int srow[4], scol[4];
#pragma unroll
    for (int j = 0; j < 4; j++) {
        int s = j * 256 + tid;
        srow[j] = s >> 3;
        scol[j] = ((s & 7) ^ (srow[j] & 7)) * 8;
    }
    const int swz0 = (quad ^ (l16 & 7)) * 8;
    const int swz1 = ((4 + quad) ^ (l16 & 7)) * 8;

    for (int kt = 0; kt < DMODEL; kt += 64) {
#pragma unroll
        for (int j = 0; j < 4; j++) {
            async16(&As[(j * 256 + w * 64) * 8],
                    A + (size_t)(m0 + srow[j]) * DMODEL + kt + scol[j]);
            async16(&Bs[(j * 256 + w * 64) * 8],
                    B + (size_t)(n0 + srow[j]) * DMODEL + kt + scol[j]);
        }
        __syncthreads();

        short8 a[4][2], b[4][2];
#pragma unroll
        for (int mi = 0; mi < 4; mi++) {
            int r = (wm * 64 + mi * 16 + l16) * 64;
            a[mi][0] = *(const short8*)&As[r + swz0];
            a[mi][1] = *(const short8*)&As[r + swz1];
        }
#pragma unroll
        for (int ni = 0; ni < 4; ni++) {
            int r = (wn * 64 + ni * 16 + l16) * 64;
            b[ni][0] = *(const short8*)&Bs[r + swz0];
            b[ni][1] = *(const short8*)&Bs[r + swz1];
        }
#pragma unroll
        for (int kk = 0; kk < 2; kk++)
#pragma unroll
            for (int mi = 0; mi < 4; mi++)
#pragma unroll
                for (int ni = 0; ni < 4; ni++)
                    acc[mi][ni] = __builtin_amdgcn_mfma_f32_16x16x32_bf16(
                        a[mi][kk], b[ni][kk], acc[mi][ni], 0, 0, 0);
        __syncthreads();
    }

#pragma unroll
    for (int ni = 0; ni < 4; ni++) {
        int ng = n0 + wn * 64 + ni * 16 + l16;
        float bv = bias[ng];
#pragma unroll
        for (int mi = 0; mi < 4; mi++) {
#pragma unroll
            for (int r = 0; r < 4; r++) {
                int mg = m0 + wm * 64 + mi * 16 + quad * 4 + r;
                out[(size_t)mg * DMODEL + ng] = acc[mi][ni][r] + bv;
            }
        }
    }
}

extern "C" void kernel_launch(void* const* d_in, const int* in_sizes, int n_in,
                              void* d_out, int out_size, void* d_ws, size_t ws_size,
                              hipStream_t stream) {
    const float* x     = (const float*)d_in[0];
    const float* w_qkv = (const float*)d_in[1];
    const float* w_out = (const float*)d_in[2];
    const float* b_out = (const float*)d_in[3];
    float* out = (float*)d_out;

    ushort_t* xb  = (ushort_t*)d_ws;                       // 8192*768
    ushort_t* wqT = xb  + (size_t)8192 * 768;              // 2304*768
    ushort_t* woT = wqT + (size_t)QKV3 * 768;              // 768*768
    ushort_t* qkv = woT + (size_t)768 * 768;               // 3*48*2048*64
    ushort_t* vT  = qkv + (size_t)3 * NHEADS * SEQ * HD;   // 48*64*2048
    ushort_t* ao  = vT  + (size_t)NHEADS * HD * SEQ;       // 8192*768

    cvt_bf16<<<dim3((8192 * 768) / 4 / 256), 256, 0, stream>>>(x, xb);
    transpose_f32_bf16<<<dim3(QKV3 / 64, DMODEL / 64), 256, 0, stream>>>(
        w_qkv, wqT, DMODEL, QKV3);
    transpose_f32_bf16<<<dim3(DMODEL / 64, DMODEL / 64), 256, 0, stream>>>(
        w_out, woT, DMODEL, DMODEL);

    gemm_qkv<<<dim3(QKV3 / 128, (BATCH * SEQ) / 128), 256, 0, stream>>>(xb, wqT, qkv);

    transpose_v<<<dim3(SEQ / 64, NHEADS), 256, 0, stream>>>(
        qkv + (size_t)2 * NHEADS * SEQ * HD, vT);

    attn<<<dim3(NHEADS * (SEQ / 128)), 256, 0, stream>>>(qkv, vT, ao);

    gemm_out<<<dim3(DMODEL / 128, (BATCH * SEQ) / 128), 256, 0, stream>>>(
        ao, woT, b_out, out);
}

// Round 5
// 228.363 us; speedup vs baseline: 2.3756x; 1.0942x over previous
//
#include <hip/hip_runtime.h>
#include <stdint.h>

typedef unsigned short ushort_t;
typedef __attribute__((ext_vector_type(8))) short short8;
typedef __attribute__((ext_vector_type(4))) short s16x4;
typedef __attribute__((ext_vector_type(4))) float f32x4;
typedef __attribute__((ext_vector_type(2))) uint32_t u32x2;

#define BATCH 4
#define SEQ 2048
#define DMODEL 768
#define NH 12
#define HD 64
#define QKV3 2304
#define NHEADS 48
// 0.125 (1/sqrt(64)) * log2(e): Q pre-scaled so softmax uses exp2
#define SCALE_Q 0.18033688011112042f

__device__ __forceinline__ ushort_t f2bf(float f) {
    union { float f; uint32_t u; } v; v.f = f;
    uint32_t u = v.u;
    u += 0x7FFF + ((u >> 16) & 1);   // RNE
    return (ushort_t)(u >> 16);
}

// pack two fp32 -> bf16x2 dword, RNE (HW packed convert when available)
__device__ __forceinline__ uint32_t pack_bf16(float a, float b) {
#if __has_builtin(__builtin_amdgcn_cvt_pk_bf16_f32)
    typedef __attribute__((ext_vector_type(2))) __bf16 bf16x2;
    bf16x2 r = __builtin_amdgcn_cvt_pk_bf16_f32(a, b);
    return __builtin_bit_cast(uint32_t, r);
#else
    return ((uint32_t)f2bf(b) << 16) | (uint32_t)f2bf(a);
#endif
}

// async global->LDS, 16B per lane; LDS dst = wave-uniform base + lane*16
typedef __attribute__((address_space(1))) uint32_t as1_u32;
typedef __attribute__((address_space(3))) uint32_t as3_u32;
__device__ __forceinline__ void async16(void* lds, const void* gsrc) {
    __builtin_amdgcn_global_load_lds((as1_u32*)gsrc, (as3_u32*)lds, 16, 0, 0);
}

// explicit vmcnt(0) lgkmcnt(0): imm16 = expcnt=7 (bits6:4), vmcnt=0, lgkmcnt=0
__device__ __forceinline__ void wait_vm_lgkm0() {
    __builtin_amdgcn_s_waitcnt(0x0070);
}

// K=16 bf16 MFMA (P^T stays in registers as the B operand)
__device__ __forceinline__ f32x4 mfma16x16x16bf16(s16x4 a, s16x4 b, f32x4 c) {
#if __has_builtin(__builtin_amdgcn_mfma_f32_16x16x16bf16_1k)
    return __builtin_amdgcn_mfma_f32_16x16x16bf16_1k(a, b, c, 0, 0, 0);
#else
    f32x4 d;
    asm volatile("v_mfma_f32_16x16x16_bf16 %0, %1, %2, %3"
                 : "=&v"(d) : "v"(a), "v"(b), "0"(c));
    return d;
#endif
}

// ---------------------------------------------------------------------------
// prep kernels
// ---------------------------------------------------------------------------
__global__ __launch_bounds__(256) void cvt_bf16(
    const float* __restrict__ in, ushort_t* __restrict__ out) {
    int i = blockIdx.x * 256 + threadIdx.x;
    float4 v = *(const float4*)(in + (size_t)i * 4);
    ushort4 o; o.x = f2bf(v.x); o.y = f2bf(v.y); o.z = f2bf(v.z); o.w = f2bf(v.w);
    *(ushort4*)(out + (size_t)i * 4) = o;
}

__global__ __launch_bounds__(256) void transpose_f32_bf16(
    const float* __restrict__ in, ushort_t* __restrict__ out, int R, int C) {
    __shared__ ushort_t t[64][72];
    const int tid = threadIdx.x;
    const int r0 = blockIdx.y * 64, c0 = blockIdx.x * 64;
#pragma unroll
    for (int i = 0; i < 4; i++) {
        int idx = tid + i * 256;
        int row = idx >> 4, c4 = (idx & 15) * 4;
        float4 v = *(const float4*)(in + (size_t)(r0 + row) * C + c0 + c4);
        ushort4 o; o.x = f2bf(v.x); o.y = f2bf(v.y); o.z = f2bf(v.z); o.w = f2bf(v.w);
        *(ushort4*)&t[row][c4] = o;
    }
    __syncthreads();
#pragma unroll
    for (int i = 0; i < 2; i++) {
        int idx = tid + i * 256;
        int oc = idx >> 3, g8 = (idx & 7) * 8;
        ushort_t tmp[8];
#pragma unroll
        for (int e = 0; e < 8; e++) tmp[e] = t[g8 + e][oc];
        *(short8*)(out + (size_t)(c0 + oc) * R + r0 + g8) = *(const short8*)tmp;
    }
}

__global__ __launch_bounds__(256) void transpose_v(
    const ushort_t* __restrict__ v, ushort_t* __restrict__ vt) {
    __shared__ ushort_t t[64][72];
    const int tid = threadIdx.x;
    const int head = blockIdx.y, n0 = blockIdx.x * 64;
    const ushort_t* src = v + (size_t)head * SEQ * HD + (size_t)n0 * HD;
#pragma unroll
    for (int i = 0; i < 2; i++) {
        int idx = tid + i * 256;
        int row = idx >> 3, c8 = (idx & 7) * 8;
        *(short8*)&t[row][c8] = *(const short8*)(src + (size_t)row * HD + c8);
    }
    __syncthreads();
    ushort_t* dst = vt + (size_t)head * HD * SEQ + n0;
#pragma unroll
    for (int i = 0; i < 2; i++) {
        int idx = tid + i * 256;
        int d = idx >> 3, g8 = (idx & 7) * 8;
        ushort_t tmp[8];
#pragma unroll
        for (int e = 0; e < 8; e++) tmp[e] = t[g8 + e][d];
        *(short8*)(dst + (size_t)d * SEQ + g8) = *(const short8*)tmp;
    }
}

// ---------------------------------------------------------------------------
// GEMM1 (unchanged)
// ---------------------------------------------------------------------------
__global__ __launch_bounds__(256, 2) void gemm_qkv(
    const ushort_t* __restrict__ A, const ushort_t* __restrict__ B,
    ushort_t* __restrict__ qkv) {
    __shared__ ushort_t As[128 * 64];
    __shared__ ushort_t Bs[128 * 64];

    const int tid = threadIdx.x;
    const int m0 = blockIdx.y * 128, n0 = blockIdx.x * 128;
    const int lane = tid & 63, w = tid >> 6;
    const int wm = w >> 1, wn = w & 1;
    const int l16 = lane & 15, quad = lane >> 4;

    f32x4 acc[4][4];
#pragma unroll
    for (int i = 0; i < 4; i++)
#pragma unroll
        for (int j = 0; j < 4; j++) acc[i][j] = (f32x4){0.f, 0.f, 0.f, 0.f};

    int srow[4], scol[4];
#pragma unroll
    for (int j = 0; j < 4; j++) {
        int s = j * 256 + tid;
        srow[j] = s >> 3;
        scol[j] = ((s & 7) ^ (srow[j] & 7)) * 8;
    }
    const int swz0 = (quad ^ (l16 & 7)) * 8;
    const int swz1 = ((4 + quad) ^ (l16 & 7)) * 8;

    for (int kt = 0; kt < DMODEL; kt += 64) {
#pragma unroll
        for (int j = 0; j < 4; j++) {
            async16(&As[(j * 256 + w * 64) * 8],
                    A + (size_t)(m0 + srow[j]) * DMODEL + kt + scol[j]);
            async16(&Bs[(j * 256 + w * 64) * 8],
                    B + (size_t)(n0 + srow[j]) * DMODEL + kt + scol[j]);
        }
        __syncthreads();

        short8 a[4][2], b[4][2];
#pragma unroll
        for (int mi = 0; mi < 4; mi++) {
            int r = (wm * 64 + mi * 16 + l16) * 64;
            a[mi][0] = *(const short8*)&As[r + swz0];
            a[mi][1] = *(const short8*)&As[r + swz1];
        }
#pragma unroll
        for (int ni = 0; ni < 4; ni++) {
            int r = (wn * 64 + ni * 16 + l16) * 64;
            b[ni][0] = *(const short8*)&Bs[r + swz0];
            b[ni][1] = *(const short8*)&Bs[r + swz1];
        }
#pragma unroll
        for (int kk = 0; kk < 2; kk++)
#pragma unroll
            for (int mi = 0; mi < 4; mi++)
#pragma unroll
                for (int ni = 0; ni < 4; ni++)
                    acc[mi][ni] = __builtin_amdgcn_mfma_f32_16x16x32_bf16(
                        a[mi][kk], b[ni][kk], acc[mi][ni], 0, 0, 0);
        __syncthreads();
    }

#pragma unroll
    for (int ni = 0; ni < 4; ni++) {
        int nbase = n0 + wn * 64 + ni * 16;
        int which = nbase / DMODEL;
        int rem = nbase - which * DMODEL;
        int h = rem >> 6;
        int d = (rem & 63) + l16;
        float scale = (which == 0) ? SCALE_Q : 1.0f;
#pragma unroll
        for (int mi = 0; mi < 4; mi++) {
#pragma unroll
            for (int r = 0; r < 4; r++) {
                int mg = m0 + wm * 64 + mi * 16 + quad * 4 + r;
                int b_ = mg >> 11, ns = mg & 2047;
                size_t dst = (((size_t)(which * BATCH + b_) * NH + h) * SEQ + ns) * HD + d;
                qkv[dst] = f2bf(acc[mi][ni][r] * scale);
            }
        }
    }
}

// ---------------------------------------------------------------------------
// Flash attention, S^T formulation, fixed-zero-max softmax, P in registers,
// 1-barrier/tile dbuf with EXPLICIT vmcnt/lgkmcnt drain before each barrier
// (do not rely on the compiler's waitcnt-before-s_barrier placement).
// ---------------------------------------------------------------------------
__global__ __launch_bounds__(256, 3) void attn(
    const ushort_t* __restrict__ qkv, const ushort_t* __restrict__ vT,
    ushort_t* __restrict__ ao) {
    __shared__ ushort_t smem[16384];

    const int tid = threadIdx.x;
    const int bh = blockIdx.x >> 4, qt = blockIdx.x & 15;
    const int lane = tid & 63, w = tid >> 6;
    const int l16 = lane & 15, quad = lane >> 4;
    const int qh7 = l16 & 7, qhi = quad >> 1, qlo4 = (quad & 1) * 4;

    const ushort_t* qh = qkv + (size_t)bh * (SEQ * HD);
    const ushort_t* kh = qkv + (size_t)(NHEADS + bh) * (SEQ * HD);
    const ushort_t* vh = vT + (size_t)bh * (HD * SEQ);

    short8 aq[2][2];
#pragma unroll
    for (int mi = 0; mi < 2; mi++)
#pragma unroll
        for (int kk = 0; kk < 2; kk++) {
            int row = qt * 128 + w * 32 + mi * 16 + l16;
            aq[mi][kk] = *(const short8*)(qh + (size_t)row * HD + kk * 32 + quad * 8);
        }

    f32x4 lv[2];          // per-lane vector l accumulators
    f32x4 O[4][2];        // O^T: [nd (d-rows)][mi (query cols)]
#pragma unroll
    for (int mi = 0; mi < 2; mi++) lv[mi] = (f32x4){0.f, 0.f, 0.f, 0.f};
#pragma unroll
    for (int nd = 0; nd < 4; nd++)
#pragma unroll
        for (int mi = 0; mi < 2; mi++) O[nd][mi] = (f32x4){0.f, 0.f, 0.f, 0.f};

    int srow[2], scol[2];
#pragma unroll
    for (int j = 0; j < 2; j++) {
        int s = j * 256 + tid;
        srow[j] = s >> 3;
        scol[j] = ((s & 7) ^ (srow[j] & 7)) * 8;
    }
    const int swz0 = (quad ^ qh7) * 8;
    const int swz1 = ((4 + quad) ^ qh7) * 8;

    // prologue: stage tile 0 into buffer 0
#pragma unroll
    for (int j = 0; j < 2; j++) {
        async16(&smem[(j * 256 + w * 64) * 8],
                kh + (size_t)srow[j] * HD + scol[j]);
        async16(&smem[4096 + (j * 256 + w * 64) * 8],
                vh + (size_t)srow[j] * SEQ + scol[j]);
    }

    const int NT = SEQ / 64;
    for (int t = 0; t < NT; t++) {
        // EXPLICIT drain: all our async global->LDS writes and LDS reads done
        // before the barrier; buffer alternation then guarantees no wave can
        // race the in-flight prefetch of any other wave.
        wait_vm_lgkm0();
        __syncthreads();
        if (t + 1 < NT) {
            int nb = ((t + 1) & 1) * 8192, j1 = (t + 1) * 64;
#pragma unroll
            for (int j = 0; j < 2; j++) {
                async16(&smem[nb + (j * 256 + w * 64) * 8],
                        kh + (size_t)(j1 + srow[j]) * HD + scol[j]);
                async16(&smem[nb + 4096 + (j * 256 + w * 64) * 8],
                        vh + (size_t)srow[j] * SEQ + j1 + scol[j]);
            }
        }
        const ushort_t* Ks = smem + (t & 1) * 8192;
        const ushort_t* Vs = Ks + 4096;

        // S^T = mfma(A=K, B=Q)
        f32x4 S[4][2];
#pragma unroll
        for (int ni = 0; ni < 4; ni++)
#pragma unroll
            for (int mi = 0; mi < 2; mi++) S[ni][mi] = (f32x4){0.f, 0.f, 0.f, 0.f};
        short8 ak[4][2];
#pragma unroll
        for (int ni = 0; ni < 4; ni++) {
            int r = (ni * 16 + l16) * 64;
            ak[ni][0] = *(const short8*)&Ks[r + swz0];
            ak[ni][1] = *(const short8*)&Ks[r + swz1];
        }
#pragma unroll
        for (int kk = 0; kk < 2; kk++)
#pragma unroll
            for (int ni = 0; ni < 4; ni++)
#pragma unroll
                for (int mi = 0; mi < 2; mi++)
                    S[ni][mi] = __builtin_amdgcn_mfma_f32_16x16x32_bf16(
                        ak[ni][kk], aq[mi][kk], S[ni][mi], 0, 0, 0);

        // softmax numerator, no max-tracking: p = exp2(s); lv += p
#pragma unroll
        for (int mi = 0; mi < 2; mi++)
#pragma unroll
            for (int ni = 0; ni < 4; ni++) {
                f32x4 p;
#pragma unroll
                for (int r = 0; r < 4; r++)
                    p[r] = __builtin_amdgcn_exp2f(S[ni][mi][r]);
                S[ni][mi] = p;
                lv[mi] += p;
            }

        // O^T += mfma(A=V^T from LDS, B=P^T packed from S regs), K=16
#pragma unroll
        for (int kb = 0; kb < 4; kb++) {
            s16x4 bp[2];
#pragma unroll
            for (int mi = 0; mi < 2; mi++) {
                uint32_t lo = pack_bf16(S[kb][mi][0], S[kb][mi][1]);
                uint32_t hi = pack_bf16(S[kb][mi][2], S[kb][mi][3]);
                bp[mi] = __builtin_bit_cast(s16x4, (u32x2){lo, hi});
            }
#pragma unroll
            for (int nd = 0; nd < 4; nd++) {
                int vrow = nd * 16 + l16;
                s16x4 av = *(const s16x4*)&Vs[vrow * 64 +
                                              (((kb * 2 + qhi) ^ qh7) * 8) + qlo4];
#pragma unroll
                for (int mi = 0; mi < 2; mi++)
                    O[nd][mi] = mfma16x16x16bf16(av, bp[mi], O[nd][mi]);
            }
        }
    }

    // epilogue: reduce l, transpose O^T via LDS, coalesced store
    float inv[2];
#pragma unroll
    for (int mi = 0; mi < 2; mi++) {
        float l = (lv[mi][0] + lv[mi][1]) + (lv[mi][2] + lv[mi][3]);
        l += __shfl_xor(l, 16, 64);
        l += __shfl_xor(l, 32, 64);
        inv[mi] = __builtin_amdgcn_rcpf(l);
    }
    wait_vm_lgkm0();
    __syncthreads();
    ushort_t* Lt = smem;   // [128][72]
#pragma unroll
    for (int mi = 0; mi < 2; mi++)
#pragma unroll
        for (int nd = 0; nd < 4; nd++) {
            int row = w * 32 + mi * 16 + l16;
            int col = nd * 16 + quad * 4;
            uint32_t d0 = pack_bf16(O[nd][mi][0] * inv[mi], O[nd][mi][1] * inv[mi]);
            uint32_t d1 = pack_bf16(O[nd][mi][2] * inv[mi], O[nd][mi][3] * inv[mi]);
            *(u32x2*)&Lt[row * 72 + col] = (u32x2){d0, d1};
        }
    __syncthreads();

    const int b_ = bh / NH, h = bh % NH;
#pragma unroll
    for (int i = 0; i < 4; i++) {
        int idx = tid + i * 256;
        int row = idx >> 3, c8 = (idx & 7) * 8;
        short8 vv = *(const short8*)&Lt[row * 72 + c8];
        *(short8*)(ao + ((size_t)(b_ * SEQ + qt * 128 + row)) * DMODEL +
                   h * HD + c8) = vv;
    }
}

// ---------------------------------------------------------------------------
// GEMM2 (unchanged)
// ---------------------------------------------------------------------------
__global__ __launch_bounds__(256, 2) void gemm_out(
    const ushort_t* __restrict__ A, const ushort_t* __restrict__ B,
    const float* __restrict__ bias, float* __restrict__ out) {
    __shared__ ushort_t As[128 * 64];
    __shared__ ushort_t Bs[128 * 64];

    const int tid = threadIdx.x;
    const int m0 = blockIdx.y * 128, n0 = blockIdx.x * 128;
    const int lane = tid & 63, w = tid >> 6;
    const int wm = w >> 1, wn = w & 1;
    const int l16 = lane & 15, quad = lane >> 4;

    f32x4 acc[4][4];
#pragma unroll
    for (int i = 0; i < 4; i++)
#pragma unroll
        for (int j = 0; j < 4; j++) acc[i][j] = (f32x4){0.f, 0.f, 0.f, 0.f};

    int srow[4], scol[4];
#pragma unroll
    for (int j = 0; j < 4; j++) {
        int s = j * 256 + tid;
        srow[j] = s >> 3;
        scol[j] = ((s & 7) ^ (srow[j] & 7)) * 8;
    }
    const int swz0 = (quad ^ (l16 & 7)) * 8;
    const int swz1 = ((4 + quad) ^ (l16 & 7)) * 8;

    for (int kt = 0; kt < DMODEL; kt += 64) {
#pragma unroll
        for (int j = 0; j < 4; j++) {
            async16(&As[(j * 256 + w * 64) * 8],
                    A + (size_t)(m0 + srow[j]) * DMODEL + kt + scol[j]);
            async16(&Bs[(j * 256 + w * 64) * 8],
                    B + (size_t)(n0 + srow[j]) * DMODEL + kt + scol[j]);
        }
        __syncthreads();

        short8 a[4][2], b[4][2];
#pragma unroll
        for (int mi = 0; mi < 4; mi++) {
            int r = (wm * 64 + mi * 16 + l16) * 64;
            a[mi][0] = *(const short8*)&As[r + swz0];
            a[mi][1] = *(const short8*)&As[r + swz1];
        }
#pragma unroll
        for (int ni = 0; ni < 4; ni++) {
            int r = (wn * 64 + ni * 16 + l16) * 64;
            b[ni][0] = *(const short8*)&Bs[r + swz0];
            b[ni][1] = *(const short8*)&Bs[r + swz1];
        }
#pragma unroll
        for (int kk = 0; kk < 2; kk++)
#pragma unroll
            for (int mi = 0; mi < 4; mi++)
#pragma unroll
                for (int ni = 0; ni < 4; ni++)
                    acc[mi][ni] = __builtin_amdgcn_mfma_f32_16x16x32_bf16(
                        a[mi][kk], b[ni][kk], acc[mi][ni], 0, 0, 0);
        __syncthreads();
    }

#pragma unroll
    for (int ni = 0; ni < 4; ni++) {
        int ng = n0 + wn * 64 + ni * 16 + l16;
        float bv = bias[ng];
#pragma unroll
        for (int mi = 0; mi < 4; mi++) {
#pragma unroll
            for (int r = 0; r < 4; r++) {
                int mg = m0 + wm * 64 + mi * 16 + quad * 4 + r;
                out[(size_t)mg * DMODEL + ng] = acc[mi][ni][r] + bv;
            }
        }
    }
}

extern "C" void kernel_launch(void* const* d_in, const int* in_sizes, int n_in,
                              void* d_out, int out_size, void* d_ws, size_t ws_size,
                              hipStream_t stream) {
    const float* x     = (const float*)d_in[0];
    const float* w_qkv = (const float*)d_in[1];
    const float* w_out = (const float*)d_in[2];
    const float* b_out = (const float*)d_in[3];
    float* out = (float*)d_out;

    ushort_t* xb  = (ushort_t*)d_ws;                       // 8192*768
    ushort_t* wqT = xb  + (size_t)8192 * 768;              // 2304*768
    ushort_t* woT = wqT + (size_t)QKV3 * 768;              // 768*768
    ushort_t* qkv = woT + (size_t)768 * 768;               // 3*48*2048*64
    ushort_t* vT  = qkv + (size_t)3 * NHEADS * SEQ * HD;   // 48*64*2048
    ushort_t* ao  = vT  + (size_t)NHEADS * HD * SEQ;       // 8192*768

    cvt_bf16<<<dim3((8192 * 768) / 4 / 256), 256, 0, stream>>>(x, xb);
    transpose_f32_bf16<<<dim3(QKV3 / 64, DMODEL / 64), 256, 0, stream>>>(
        w_qkv, wqT, DMODEL, QKV3);
    transpose_f32_bf16<<<dim3(DMODEL / 64, DMODEL / 64), 256, 0, stream>>>(
        w_out, woT, DMODEL, DMODEL);

    gemm_qkv<<<dim3(QKV3 / 128, (BATCH * SEQ) / 128), 256, 0, stream>>>(xb, wqT, qkv);

    transpose_v<<<dim3(SEQ / 64, NHEADS), 256, 0, stream>>>(
        qkv + (size_t)2 * NHEADS * SEQ * HD, vT);

    attn<<<dim3(NHEADS * (SEQ / 128)), 256, 0, stream>>>(qkv, vT, ao);

    gemm_out<<<dim3(DMODEL / 128, (BATCH * SEQ) / 128), 256, 0, stream>>>(
        ao, woT, b_out, out);
}

// Round 6
// 218.536 us; speedup vs baseline: 2.4824x; 1.0450x over previous
//
#include <hip/hip_runtime.h>
#include <stdint.h>

typedef unsigned short ushort_t;
typedef __attribute__((ext_vector_type(8))) short short8;
typedef __attribute__((ext_vector_type(4))) short s16x4;
typedef __attribute__((ext_vector_type(4))) float f32x4;
typedef __attribute__((ext_vector_type(2))) uint32_t u32x2;

#define BATCH 4
#define SEQ 2048
#define DMODEL 768
#define NH 12
#define HD 64
#define QKV3 2304
#define NHEADS 48
// 0.125 (1/sqrt(64)) * log2(e): Q pre-scaled so softmax uses exp2
#define SCALE_Q 0.18033688011112042f

__device__ __forceinline__ ushort_t f2bf(float f) {
    union { float f; uint32_t u; } v; v.f = f;
    uint32_t u = v.u;
    u += 0x7FFF + ((u >> 16) & 1);   // RNE
    return (ushort_t)(u >> 16);
}

// pack two fp32 -> bf16x2 dword, RNE (HW packed convert when available)
__device__ __forceinline__ uint32_t pack_bf16(float a, float b) {
#if __has_builtin(__builtin_amdgcn_cvt_pk_bf16_f32)
    typedef __attribute__((ext_vector_type(2))) __bf16 bf16x2;
    bf16x2 r = __builtin_amdgcn_cvt_pk_bf16_f32(a, b);
    return __builtin_bit_cast(uint32_t, r);
#else
    return ((uint32_t)f2bf(b) << 16) | (uint32_t)f2bf(a);
#endif
}

// async global->LDS, 16B per lane; LDS dst = wave-uniform base + lane*16
typedef __attribute__((address_space(1))) uint32_t as1_u32;
typedef __attribute__((address_space(3))) uint32_t as3_u32;
__device__ __forceinline__ void async16(void* lds, const void* gsrc) {
    __builtin_amdgcn_global_load_lds((as1_u32*)gsrc, (as3_u32*)lds, 16, 0, 0);
}

// explicit vmcnt(0) lgkmcnt(0) drain (required before barrier w/ async LDS)
__device__ __forceinline__ void wait_vm_lgkm0() {
    __builtin_amdgcn_s_waitcnt(0x0070);
}

// K=16 bf16 MFMA (P^T stays in registers as the B operand)
__device__ __forceinline__ f32x4 mfma16x16x16bf16(s16x4 a, s16x4 b, f32x4 c) {
#if __has_builtin(__builtin_amdgcn_mfma_f32_16x16x16bf16_1k)
    return __builtin_amdgcn_mfma_f32_16x16x16bf16_1k(a, b, c, 0, 0, 0);
#else
    f32x4 d;
    asm volatile("v_mfma_f32_16x16x16_bf16 %0, %1, %2, %3"
                 : "=&v"(d) : "v"(a), "v"(b), "0"(c));
    return d;
#endif
}

// ---------------------------------------------------------------------------
// prep kernels
// ---------------------------------------------------------------------------
__global__ __launch_bounds__(256) void cvt_bf16(
    const float* __restrict__ in, ushort_t* __restrict__ out) {
    int i = blockIdx.x * 256 + threadIdx.x;
    float4 v = *(const float4*)(in + (size_t)i * 4);
    ushort4 o; o.x = f2bf(v.x); o.y = f2bf(v.y); o.z = f2bf(v.z); o.w = f2bf(v.w);
    *(ushort4*)(out + (size_t)i * 4) = o;
}

__global__ __launch_bounds__(256) void transpose_f32_bf16(
    const float* __restrict__ in, ushort_t* __restrict__ out, int R, int C) {
    __shared__ ushort_t t[64][72];
    const int tid = threadIdx.x;
    const int r0 = blockIdx.y * 64, c0 = blockIdx.x * 64;
#pragma unroll
    for (int i = 0; i < 4; i++) {
        int idx = tid + i * 256;
        int row = idx >> 4, c4 = (idx & 15) * 4;
        float4 v = *(const float4*)(in + (size_t)(r0 + row) * C + c0 + c4);
        ushort4 o; o.x = f2bf(v.x); o.y = f2bf(v.y); o.z = f2bf(v.z); o.w = f2bf(v.w);
        *(ushort4*)&t[row][c4] = o;
    }
    __syncthreads();
#pragma unroll
    for (int i = 0; i < 2; i++) {
        int idx = tid + i * 256;
        int oc = idx >> 3, g8 = (idx & 7) * 8;
        ushort_t tmp[8];
#pragma unroll
        for (int e = 0; e < 8; e++) tmp[e] = t[g8 + e][oc];
        *(short8*)(out + (size_t)(c0 + oc) * R + r0 + g8) = *(const short8*)tmp;
    }
}

// ---------------------------------------------------------------------------
// GEMM1: qkv = xb @ wqT^T. Q/K scattered to [which][b][h][n][d] (Q scaled);
// V written DIRECTLY transposed to vT[b*12+h][d][n] (8B token-packed stores).
// ---------------------------------------------------------------------------
__global__ __launch_bounds__(256, 2) void gemm_qkv(
    const ushort_t* __restrict__ A, const ushort_t* __restrict__ B,
    ushort_t* __restrict__ qkv, ushort_t* __restrict__ vT) {
    __shared__ ushort_t As[128 * 64];
    __shared__ ushort_t Bs[128 * 64];

    const int tid = threadIdx.x;
    const int m0 = blockIdx.y * 128, n0 = blockIdx.x * 128;
    const int lane = tid & 63, w = tid >> 6;
    const int wm = w >> 1, wn = w & 1;
    const int l16 = lane & 15, quad = lane >> 4;

    f32x4 acc[4][4];
#pragma unroll
    for (int i = 0; i < 4; i++)
#pragma unroll
        for (int j = 0; j < 4; j++) acc[i][j] = (f32x4){0.f, 0.f, 0.f, 0.f};

    int srow[4], scol[4];
#pragma unroll
    for (int j = 0; j < 4; j++) {
        int s = j * 256 + tid;
        srow[j] = s >> 3;
        scol[j] = ((s & 7) ^ (srow[j] & 7)) * 8;
    }
    const int swz0 = (quad ^ (l16 & 7)) * 8;
    const int swz1 = ((4 + quad) ^ (l16 & 7)) * 8;

    for (int kt = 0; kt < DMODEL; kt += 64) {
#pragma unroll
        for (int j = 0; j < 4; j++) {
            async16(&As[(j * 256 + w * 64) * 8],
                    A + (size_t)(m0 + srow[j]) * DMODEL + kt + scol[j]);
            async16(&Bs[(j * 256 + w * 64) * 8],
                    B + (size_t)(n0 + srow[j]) * DMODEL + kt + scol[j]);
        }
        wait_vm_lgkm0();
        __syncthreads();

        short8 a[4][2], b[4][2];
#pragma unroll
        for (int mi = 0; mi < 4; mi++) {
            int r = (wm * 64 + mi * 16 + l16) * 64;
            a[mi][0] = *(const short8*)&As[r + swz0];
            a[mi][1] = *(const short8*)&As[r + swz1];
        }
#pragma unroll
        for (int ni = 0; ni < 4; ni++) {
            int r = (wn * 64 + ni * 16 + l16) * 64;
            b[ni][0] = *(const short8*)&Bs[r + swz0];
            b[ni][1] = *(const short8*)&Bs[r + swz1];
        }
#pragma unroll
        for (int kk = 0; kk < 2; kk++)
#pragma unroll
            for (int mi = 0; mi < 4; mi++)
#pragma unroll
                for (int ni = 0; ni < 4; ni++)
                    acc[mi][ni] = __builtin_amdgcn_mfma_f32_16x16x32_bf16(
                        a[mi][kk], b[ni][kk], acc[mi][ni], 0, 0, 0);
        __syncthreads();
    }

#pragma unroll
    for (int ni = 0; ni < 4; ni++) {
        int nbase = n0 + wn * 64 + ni * 16;
        int which = nbase / DMODEL;           // block-uniform per ni
        int rem = nbase - which * DMODEL;
        int h = rem >> 6;
        int d = (rem & 63) + l16;
        if (which == 2) {
            // V^T direct: [b*12+h][d][token], 4 consecutive tokens per lane
#pragma unroll
            for (int mi = 0; mi < 4; mi++) {
                int mg = m0 + wm * 64 + mi * 16 + quad * 4;
                int b_ = mg >> 11, ns = mg & 2047;
                u32x2 pk = {pack_bf16(acc[mi][ni][0], acc[mi][ni][1]),
                            pack_bf16(acc[mi][ni][2], acc[mi][ni][3])};
                *(u32x2*)(vT + ((size_t)(b_ * NH + h) * HD + d) * SEQ + ns) = pk;
            }
        } else {
            float scale = (which == 0) ? SCALE_Q : 1.0f;
#pragma unroll
            for (int mi = 0; mi < 4; mi++) {
#pragma unroll
                for (int r = 0; r < 4; r++) {
                    int mg = m0 + wm * 64 + mi * 16 + quad * 4 + r;
                    int b_ = mg >> 11, ns = mg & 2047;
                    size_t dst = (((size_t)(which * BATCH + b_) * NH + h) * SEQ + ns) * HD + d;
                    qkv[dst] = f2bf(acc[mi][ni][r] * scale);
                }
            }
        }
    }
}

// ---------------------------------------------------------------------------
// Flash attention, S^T form, fixed-zero-max softmax, per-ni pipelined
// QK->exp->pack->PV stages, XCD-swizzled block mapping for K/V L2 locality.
// ---------------------------------------------------------------------------
__global__ __launch_bounds__(256, 3) void attn(
    const ushort_t* __restrict__ qkv, const ushort_t* __restrict__ vT,
    ushort_t* __restrict__ ao) {
    __shared__ ushort_t smem[16384];

    const int tid = threadIdx.x;
    // XCD swizzle: all 16 Q-blocks of a head land on one XCD (bid%8 == XCD)
    const int bid = blockIdx.x;
    const int i = bid >> 3;
    const int bh = (bid & 7) + 8 * (i % 6);
    const int qt = i / 6;
    const int lane = tid & 63, w = tid >> 6;
    const int l16 = lane & 15, quad = lane >> 4;
    const int qh7 = l16 & 7, qhi = quad >> 1, qlo4 = (quad & 1) * 4;

    const ushort_t* qh = qkv + (size_t)bh * (SEQ * HD);
    const ushort_t* kh = qkv + (size_t)(NHEADS + bh) * (SEQ * HD);
    const ushort_t* vh = vT + (size_t)bh * (HD * SEQ);

    short8 aq[2][2];
#pragma unroll
    for (int mi = 0; mi < 2; mi++)
#pragma unroll
        for (int kk = 0; kk < 2; kk++) {
            int row = qt * 128 + w * 32 + mi * 16 + l16;
            aq[mi][kk] = *(const short8*)(qh + (size_t)row * HD + kk * 32 + quad * 8);
        }

    f32x4 lv[2];
    f32x4 O[4][2];
#pragma unroll
    for (int mi = 0; mi < 2; mi++) lv[mi] = (f32x4){0.f, 0.f, 0.f, 0.f};
#pragma unroll
    for (int nd = 0; nd < 4; nd++)
#pragma unroll
        for (int mi = 0; mi < 2; mi++) O[nd][mi] = (f32x4){0.f, 0.f, 0.f, 0.f};

    int srow[2], scol[2];
#pragma unroll
    for (int j = 0; j < 2; j++) {
        int s = j * 256 + tid;
        srow[j] = s >> 3;
        scol[j] = ((s & 7) ^ (srow[j] & 7)) * 8;
    }
    const int swz0 = (quad ^ qh7) * 8;
    const int swz1 = ((4 + quad) ^ qh7) * 8;

    // prologue: stage tile 0 into buffer 0
#pragma unroll
    for (int j = 0; j < 2; j++) {
        async16(&smem[(j * 256 + w * 64) * 8],
                kh + (size_t)srow[j] * HD + scol[j]);
        async16(&smem[4096 + (j * 256 + w * 64) * 8],
                vh + (size_t)srow[j] * SEQ + scol[j]);
    }

    const int NT = SEQ / 64;
    for (int t = 0; t < NT; t++) {
        wait_vm_lgkm0();
        __syncthreads();
        if (t + 1 < NT) {
            int nb = ((t + 1) & 1) * 8192, j1 = (t + 1) * 64;
#pragma unroll
            for (int j = 0; j < 2; j++) {
                async16(&smem[nb + (j * 256 + w * 64) * 8],
                        kh + (size_t)(j1 + srow[j]) * HD + scol[j]);
                async16(&smem[nb + 4096 + (j * 256 + w * 64) * 8],
                        vh + (size_t)srow[j] * SEQ + j1 + scol[j]);
            }
        }
        const ushort_t* Ks = smem + (t & 1) * 8192;
        const ushort_t* Vs = Ks + 4096;

        // per-ni fused pipeline: QK(ni) -> exp(ni) -> pack(ni) -> PV(ni)
        // (independent register streams per ni let the scheduler overlap
        //  MFMA of ni+1 with exp/pack of ni)
#pragma unroll
        for (int ni = 0; ni < 4; ni++) {
            int r = (ni * 16 + l16) * 64;
            short8 ak0 = *(const short8*)&Ks[r + swz0];
            short8 ak1 = *(const short8*)&Ks[r + swz1];
            s16x4 bp[2];
#pragma unroll
            for (int mi = 0; mi < 2; mi++) {
                f32x4 s = __builtin_amdgcn_mfma_f32_16x16x32_bf16(
                    ak0, aq[mi][0], (f32x4){0.f, 0.f, 0.f, 0.f}, 0, 0, 0);
                s = __builtin_amdgcn_mfma_f32_16x16x32_bf16(
                    ak1, aq[mi][1], s, 0, 0, 0);
                f32x4 p;
#pragma unroll
                for (int rr = 0; rr < 4; rr++)
                    p[rr] = __builtin_amdgcn_exp2f(s[rr]);
                lv[mi] += p;
                bp[mi] = __builtin_bit_cast(
                    s16x4, (u32x2){pack_bf16(p[0], p[1]), pack_bf16(p[2], p[3])});
            }
#pragma unroll
            for (int nd = 0; nd < 4; nd++) {
                int vrow = nd * 16 + l16;
                s16x4 av = *(const s16x4*)&Vs[vrow * 64 +
                                              (((ni * 2 + qhi) ^ qh7) * 8) + qlo4];
#pragma unroll
                for (int mi = 0; mi < 2; mi++)
                    O[nd][mi] = mfma16x16x16bf16(av, bp[mi], O[nd][mi]);
            }
        }
    }

    // epilogue: reduce l, transpose O^T via LDS, coalesced store
    float inv[2];
#pragma unroll
    for (int mi = 0; mi < 2; mi++) {
        float l = (lv[mi][0] + lv[mi][1]) + (lv[mi][2] + lv[mi][3]);
        l += __shfl_xor(l, 16, 64);
        l += __shfl_xor(l, 32, 64);
        inv[mi] = __builtin_amdgcn_rcpf(l);
    }
    wait_vm_lgkm0();
    __syncthreads();
    ushort_t* Lt = smem;   // [128][72]
#pragma unroll
    for (int mi = 0; mi < 2; mi++)
#pragma unroll
        for (int nd = 0; nd < 4; nd++) {
            int row = w * 32 + mi * 16 + l16;
            int col = nd * 16 + quad * 4;
            uint32_t d0 = pack_bf16(O[nd][mi][0] * inv[mi], O[nd][mi][1] * inv[mi]);
            uint32_t d1 = pack_bf16(O[nd][mi][2] * inv[mi], O[nd][mi][3] * inv[mi]);
            *(u32x2*)&Lt[row * 72 + col] = (u32x2){d0, d1};
        }
    __syncthreads();

    const int b_ = bh / NH, h = bh % NH;
#pragma unroll
    for (int i2 = 0; i2 < 4; i2++) {
        int idx = tid + i2 * 256;
        int row = idx >> 3, c8 = (idx & 7) * 8;
        short8 vv = *(const short8*)&Lt[row * 72 + c8];
        *(short8*)(ao + ((size_t)(b_ * SEQ + qt * 128 + row)) * DMODEL +
                   h * HD + c8) = vv;
    }
}

// ---------------------------------------------------------------------------
// GEMM2 (unchanged)
// ---------------------------------------------------------------------------
__global__ __launch_bounds__(256, 2) void gemm_out(
    const ushort_t* __restrict__ A, const ushort_t* __restrict__ B,
    const float* __restrict__ bias, float* __restrict__ out) {
    __shared__ ushort_t As[128 * 64];
    __shared__ ushort_t Bs[128 * 64];

    const int tid = threadIdx.x;
    const int m0 = blockIdx.y * 128, n0 = blockIdx.x * 128;
    const int lane = tid & 63, w = tid >> 6;
    const int wm = w >> 1, wn = w & 1;
    const int l16 = lane & 15, quad = lane >> 4;

    f32x4 acc[4][4];
#pragma unroll
    for (int i = 0; i < 4; i++)
#pragma unroll
        for (int j = 0; j < 4; j++) acc[i][j] = (f32x4){0.f, 0.f, 0.f, 0.f};

    int srow[4], scol[4];
#pragma unroll
    for (int j = 0; j < 4; j++) {
        int s = j * 256 + tid;
        srow[j] = s >> 3;
        scol[j] = ((s & 7) ^ (srow[j] & 7)) * 8;
    }
    const int swz0 = (quad ^ (l16 & 7)) * 8;
    const int swz1 = ((4 + quad) ^ (l16 & 7)) * 8;

    for (int kt = 0; kt < DMODEL; kt += 64) {
#pragma unroll
        for (int j = 0; j < 4; j++) {
            async16(&As[(j * 256 + w * 64) * 8],
                    A + (size_t)(m0 + srow[j]) * DMODEL + kt + scol[j]);
            async16(&Bs[(j * 256 + w * 64) * 8],
                    B + (size_t)(n0 + srow[j]) * DMODEL + kt + scol[j]);
        }
        wait_vm_lgkm0();
        __syncthreads();

        short8 a[4][2], b[4][2];
#pragma unroll
        for (int mi = 0; mi < 4; mi++) {
            int r = (wm * 64 + mi * 16 + l16) * 64;
            a[mi][0] = *(const short8*)&As[r + swz0];
            a[mi][1] = *(const short8*)&As[r + swz1];
        }
#pragma unroll
        for (int ni = 0; ni < 4; ni++) {
            int r = (wn * 64 + ni * 16 + l16) * 64;
            b[ni][0] = *(const short8*)&Bs[r + swz0];
            b[ni][1] = *(const short8*)&Bs[r + swz1];
        }
#pragma unroll
        for (int kk = 0; kk < 2; kk++)
#pragma unroll
            for (int mi = 0; mi < 4; mi++)
#pragma unroll
                for (int ni = 0; ni < 4; ni++)
                    acc[mi][ni] = __builtin_amdgcn_mfma_f32_16x16x32_bf16(
                        a[mi][kk], b[ni][kk], acc[mi][ni], 0, 0, 0);
        __syncthreads();
    }

#pragma unroll
    for (int ni = 0; ni < 4; ni++) {
        int ng = n0 + wn * 64 + ni * 16 + l16;
        float bv = bias[ng];
#pragma unroll
        for (int mi = 0; mi < 4; mi++) {
#pragma unroll
            for (int r = 0; r < 4; r++) {
                int mg = m0 + wm * 64 + mi * 16 + quad * 4 + r;
                out[(size_t)mg * DMODEL + ng] = acc[mi][ni][r] + bv;
            }
        }
    }
}

extern "C" void kernel_launch(void* const* d_in, const int* in_sizes, int n_in,
                              void* d_out, int out_size, void* d_ws, size_t ws_size,
                              hipStream_t stream) {
    const float* x     = (const float*)d_in[0];
    const float* w_qkv = (const float*)d_in[1];
    const float* w_out = (const float*)d_in[2];
    const float* b_out = (const float*)d_in[3];
    float* out = (float*)d_out;

    ushort_t* xb  = (ushort_t*)d_ws;                       // 8192*768
    ushort_t* wqT = xb  + (size_t)8192 * 768;              // 2304*768
    ushort_t* woT = wqT + (size_t)QKV3 * 768;              // 768*768
    ushort_t* qkv = woT + (size_t)768 * 768;               // 3*48*2048*64 (V region unused)
    ushort_t* vT  = qkv + (size_t)3 * NHEADS * SEQ * HD;   // 48*64*2048
    ushort_t* ao  = vT  + (size_t)NHEADS * HD * SEQ;       // 8192*768

    cvt_bf16<<<dim3((8192 * 768) / 4 / 256), 256, 0, stream>>>(x, xb);
    transpose_f32_bf16<<<dim3(QKV3 / 64, DMODEL / 64), 256, 0, stream>>>(
        w_qkv, wqT, DMODEL, QKV3);
    transpose_f32_bf16<<<dim3(DMODEL / 64, DMODEL / 64), 256, 0, stream>>>(
        w_out, woT, DMODEL, DMODEL);

    gemm_qkv<<<dim3(QKV3 / 128, (BATCH * SEQ) / 128), 256, 0, stream>>>(
        xb, wqT, qkv, vT);

    attn<<<dim3(NHEADS * (SEQ / 128)), 256, 0, stream>>>(qkv, vT, ao);

    gemm_out<<<dim3(DMODEL / 128, (BATCH * SEQ) / 128), 256, 0, stream>>>(
        ao, woT, b_out, out);
}